// Round 8
// baseline (466.522 us; speedup 1.0000x reference)
//
#include <hip/hip_runtime.h>
#include <hip/hip_bf16.h>
#include <math.h>

#define TWO_PI_256 0.024543692606170259678f  // 2*pi/256

typedef __attribute__((ext_vector_type(8))) short bf16x8;
typedef __attribute__((ext_vector_type(4))) float f32x4;

static __device__ __forceinline__ ushort bf16_rn(float a) {
    union { float f; unsigned int u; } v; v.f = a;
    unsigned int r = v.u + 0x7FFFu + ((v.u >> 16) & 1u);
    return (ushort)(r >> 16);
}
static __device__ __forceinline__ float bf16_to_f(ushort h) {
    union { unsigned int u; float f; } v; v.u = ((unsigned int)h) << 16;
    return v.f;
}
static __device__ __forceinline__ void split2(float a, ushort& hi, ushort& lo) {
    ushort h = bf16_rn(a);
    hi = h;
    lo = bf16_rn(a - bf16_to_f(h));
}

// hw cvt_pk path: 8 floats -> bf16-hi x8 + bf16-lo x8
static __device__ __forceinline__ void split8(const float* v, bf16x8& hi8, bf16x8& lo8) {
    union { ushort u[8]; bf16x8 v8; } H, L;
    #pragma unroll
    for (int j = 0; j < 8; j += 2) {
        __hip_bfloat162 hb = __float22bfloat162_rn(make_float2(v[j], v[j + 1]));
        ushort2 hu = *reinterpret_cast<ushort2*>(&hb);
        float fx = __uint_as_float((unsigned int)hu.x << 16);
        float fy = __uint_as_float((unsigned int)hu.y << 16);
        __hip_bfloat162 lb = __float22bfloat162_rn(make_float2(v[j] - fx, v[j + 1] - fy));
        ushort2 lu = *reinterpret_cast<ushort2*>(&lb);
        H.u[j] = hu.x; H.u[j + 1] = hu.y;
        L.u[j] = lu.x; L.u[j + 1] = lu.y;
    }
    hi8 = H.v8; lo8 = L.v8;
}

// branchless tanh-form GELU (max |delta| vs exact-erf gelu ~5e-4)
static __device__ __forceinline__ float gelu_f(float v) {
    float z = v * fmaf(v * v, 0.10294321f, 2.3022082f);   // 2u/ln2
    float e = __builtin_amdgcn_exp2f(z);
    return v - v * __builtin_amdgcn_rcpf(e + 1.0f);
}

// ---------------- Pass 0: bf16-split tables ----------------
__global__ __launch_bounds__(256) void k_prep(const float* __restrict__ Wc,
        ushort* __restrict__ Wch, ushort* __restrict__ Wcl,
        ushort* __restrict__ Tgh, ushort* __restrict__ Tgl,
        ushort* __restrict__ Tkh, ushort* __restrict__ Tkl,
        ushort* __restrict__ Th2h, ushort* __restrict__ Th2l,
        ushort* __restrict__ Th4h, ushort* __restrict__ Th4l) {
    int g = blockIdx.x * 256 + threadIdx.x;
    if (g < 4096) {
        ushort h, l; split2(Wc[g], h, l);
        Wch[g] = h; Wcl[g] = l;
    }
    int t = g - 4096;
    if (t >= 0 && t < 8192) {
        int w = t >> 5, kz = t & 31, kx = kz & 15;
        int ph = (w * kx) & 255;
        float s, c; sincosf((float)ph * TWO_PI_256, &s, &c);
        float val = (kz < 16) ? c : s;
        ushort h, l; split2(val, h, l);
        Tgh[t] = h; Tgl[t] = l;
    }
    int t2 = g - 12288;
    if (t2 >= 0 && t2 < 8192) {
        int j = t2 >> 8, w = t2 & 255, kx = j & 15;
        int ph = (w * kx) & 255;
        float s, c; sincosf((float)ph * TWO_PI_256, &s, &c);
        float val = (j < 16) ? c : s;
        ushort h, l; split2(val, h, l);
        Tkh[t2] = h; Tkl[t2] = l;
    }
    int t3 = g - 20480;
    if (t3 >= 0 && t3 < 16384) {
        int row = t3 >> 8, h = t3 & 255;
        int ky = row & 31;
        int phys = (ky < 16) ? ky : (224 + ky);
        int ph = (phys * h) & 255;
        float s, c; sincosf((float)ph * TWO_PI_256, &s, &c);
        float val = (row < 32) ? c : s;
        ushort hh, ll; split2(val, hh, ll);
        Th2h[t3] = hh; Th2l[t3] = ll;
    }
    int t4 = g - 36864;
    if (t4 >= 0 && t4 < 16384) {
        int h = t4 >> 6, col = t4 & 63;
        int ky = col & 31;
        int phys = (ky < 16) ? ky : (224 + ky);
        int ph = (phys * h) & 255;
        float s, c; sincosf((float)ph * TWO_PI_256, &s, &c);
        float val = (col < 32) ? c : s;
        ushort hh, ll; split2(val, hh, ll);
        Th4h[t4] = hh; Th4l[t4] = ll;
    }
}

// ---------------- Pass 1+2 fused: w-DFT then h-DFT, one block per plane ----------------
__global__ __launch_bounds__(256) void k_spec(const float* __restrict__ x,
        const ushort* __restrict__ Tkh, const ushort* __restrict__ Tkl,
        const ushort* __restrict__ Th2h, const ushort* __restrict__ Th2l,
        float2* __restrict__ XhT) {
    const int tid = threadIdx.x;
    const int lane = tid & 63;
    const int wv = tid >> 6;
    const int bid = blockIdx.x;
    const int bc = ((bid & 7) << 7) + (bid >> 3);     // XCD-chunked (bijective, 1024 = 8*128)
    const int l15 = lane & 15, l4 = lane >> 4;
    const int mt = wv >> 1, nt = wv & 1;

    __shared__ ushort Ah[32 * 256];    // chunk x bf16-hi, octet^(h&7) swizzled
    __shared__ ushort Al[32 * 256];
    __shared__ ushort Xwh[32 * 256];   // [col][h] bf16-hi, h-octet^(col&7) swizzled
    __shared__ ushort Xwl[32 * 256];
    __shared__ float  Dl[64 * 33];

    const float* xp = x + ((size_t)bc << 16);

    const int rbase = ((mt << 4) + l15) << 8;          // A row base (ushorts)
    const int rs = ((mt << 4) + l15) & 7;
    const int jrow = (nt << 4) + l15;                  // Tk row / Xw col

#define LDCH(pf, c) { \
    _Pragma("unroll") \
    for (int i_ = 0; i_ < 4; ++i_) { \
        int f8_ = tid + (i_ << 8); \
        int hh_ = f8_ >> 5, oct_ = f8_ & 31; \
        const float* p_ = xp + (((c) << 5) + hh_) * 256 + (oct_ << 3); \
        *(float4*)&pf[i_ * 8]     = *(const float4*)(p_); \
        *(float4*)&pf[i_ * 8 + 4] = *(const float4*)(p_ + 4); \
    } }

#define STAGE_A(pf) { \
    _Pragma("unroll") \
    for (int i_ = 0; i_ < 4; ++i_) { \
        int f8_ = tid + (i_ << 8); \
        int hh_ = f8_ >> 5, oct_ = f8_ & 31; \
        bf16x8 hi8_, lo8_; \
        split8(&pf[i_ * 8], hi8_, lo8_); \
        int bx_ = oct_ ^ (hh_ & 7); \
        *(bf16x8*)(&Ah[(hh_ << 8) + (bx_ << 3)]) = hi8_; \
        *(bf16x8*)(&Al[(hh_ << 8) + (bx_ << 3)]) = lo8_; \
    } }

    float pfA[32], pfB[32];
    LDCH(pfA, 0);
    LDCH(pfB, 1);

    #pragma unroll
    for (int c = 0; c < 8; ++c) {
        __syncthreads();                 // prior chunk's A reads complete
        if (c & 1) { STAGE_A(pfB); } else { STAGE_A(pfA); }
        __syncthreads();
        if (c + 2 < 8) {                 // refill the just-consumed buffer
            if (c & 1) { LDCH(pfB, c + 2); } else { LDCH(pfA, c + 2); }
        }

        f32x4 acc = {0.f, 0.f, 0.f, 0.f};
        #pragma unroll
        for (int ks = 0; ks < 8; ++ks) {
            int boff = ((((ks << 2) + l4) ^ rs) << 3);
            bf16x8 a_h = *(const bf16x8*)(&Ah[rbase + boff]);
            bf16x8 a_l = *(const bf16x8*)(&Al[rbase + boff]);
            int toff = (jrow << 8) + (ks << 5) + (l4 << 3);
            bf16x8 b_h = *(const bf16x8*)(Tkh + toff);
            bf16x8 b_l = *(const bf16x8*)(Tkl + toff);
            acc = __builtin_amdgcn_mfma_f32_16x16x32_bf16(a_h, b_h, acc, 0, 0, 0);
            acc = __builtin_amdgcn_mfma_f32_16x16x32_bf16(a_h, b_l, acc, 0, 0, 0);
            acc = __builtin_amdgcn_mfma_f32_16x16x32_bf16(a_l, b_h, acc, 0, 0, 0);
        }
        // D: col=jrow, h = c*32 + mt*16 + l4*4 + r. nt=1 rows are sin -> Im = -acc.
        ushort hi4[4], lo4[4];
        #pragma unroll
        for (int r = 0; r < 4; ++r) {
            float v = nt ? -acc[r] : acc[r];
            split2(v, hi4[r], lo4[r]);
        }
        int habs = (c << 5) + (mt << 4) + (l4 << 2);
        int op = (habs >> 3) ^ (jrow & 7);
        int addr = (jrow << 8) + (op << 3) + (habs & 7);
        *(ushort4*)(&Xwh[addr]) = *(ushort4*)hi4;
        *(ushort4*)(&Xwl[addr]) = *(ushort4*)lo4;
    }
    __syncthreads();                     // Xw writes visible

    // ---- h-DFT: D2[64 ky'][32 col] = Th2 * Xw ----
    f32x4 acc2[2];
    acc2[0] = (f32x4){0.f, 0.f, 0.f, 0.f};
    acc2[1] = (f32x4){0.f, 0.f, 0.f, 0.f};
    const int arow = (wv << 4) + l15;
    #pragma unroll
    for (int ks = 0; ks < 8; ++ks) {
        int aoff = (arow << 8) + (ks << 5) + (l4 << 3);
        bf16x8 a_h = *(const bf16x8*)(Th2h + aoff);
        bf16x8 a_l = *(const bf16x8*)(Th2l + aoff);
        #pragma unroll
        for (int nt2 = 0; nt2 < 2; ++nt2) {
            int col = (nt2 << 4) + l15;
            int oi = ((ks << 2) + l4) ^ (col & 7);
            bf16x8 b_h = *(const bf16x8*)(&Xwh[(col << 8) + (oi << 3)]);
            bf16x8 b_l = *(const bf16x8*)(&Xwl[(col << 8) + (oi << 3)]);
            acc2[nt2] = __builtin_amdgcn_mfma_f32_16x16x32_bf16(a_h, b_h, acc2[nt2], 0, 0, 0);
            acc2[nt2] = __builtin_amdgcn_mfma_f32_16x16x32_bf16(a_h, b_l, acc2[nt2], 0, 0, 0);
            acc2[nt2] = __builtin_amdgcn_mfma_f32_16x16x32_bf16(a_l, b_h, acc2[nt2], 0, 0, 0);
        }
    }
    #pragma unroll
    for (int nt2 = 0; nt2 < 2; ++nt2)
        #pragma unroll
        for (int r = 0; r < 4; ++r)
            Dl[((wv << 4) + (l4 << 2) + r) * 33 + (nt2 << 4) + l15] = acc2[nt2][r];
    __syncthreads();

    #pragma unroll
    for (int q = 0; q < 2; ++q) {
        int m = tid + (q << 8);
        int ky = m >> 4, kx = m & 15;
        float re = Dl[ky * 33 + kx] + Dl[(32 + ky) * 33 + 16 + kx];
        float im = Dl[ky * 33 + 16 + kx] - Dl[(32 + ky) * 33 + kx];
        XhT[((size_t)m << 10) + bc] = make_float2(re, im);
    }
#undef LDCH
#undef STAGE_A
}

// ---------------- Pass 3: channel mix, coalesced-weight version ----------------
__global__ __launch_bounds__(256) void k_modes(const float2* __restrict__ XhT,
        const float* __restrict__ w1r, const float* __restrict__ w1i,
        const float* __restrict__ w2r, const float* __restrict__ w2i,
        float2* __restrict__ S) {
    const int tid = threadIdx.x;
    const int kyIdx = blockIdx.x >> 3;
    const int oc    = blockIdx.x & 7;
    const int xy0   = (kyIdx & 15) << 4;
    const float* __restrict__ wr = (kyIdx < 16) ? w1r : w2r;
    const float* __restrict__ wi = (kyIdx < 16) ? w1i : w2i;

    __shared__ float2 Xl[16][16][17];
    __shared__ float  Wr_l[16][8][20];
    __shared__ float  Wi_l[16][8][20];

    const int b  = tid >> 4;
    const int o8 = (tid >> 1) & 7;
    const int kh = tid & 1;

    const int s_ii = tid >> 4, s_oj = (tid >> 1) & 7, s_part = tid & 1;
    const int s_kx = tid >> 4, s_bb = tid & 15;

    float2 acc[8];
    #pragma unroll
    for (int j = 0; j < 8; ++j) acc[j] = make_float2(0.f, 0.f);

    for (int ic = 0; ic < 4; ++ic) {
        if (ic) __syncthreads();
        {
            const float* src = s_part ? wi : wr;
            size_t off = ((size_t)(((ic << 4) + s_ii) * 64 + (oc << 3) + s_oj) << 8) + xy0;
            float4 v0 = *(const float4*)(src + off);
            float4 v1 = *(const float4*)(src + off + 4);
            float4 v2 = *(const float4*)(src + off + 8);
            float4 v3 = *(const float4*)(src + off + 12);
            float* dst = s_part ? &Wi_l[s_ii][s_oj][0] : &Wr_l[s_ii][s_oj][0];
            *(float4*)(dst)      = v0;
            *(float4*)(dst + 4)  = v1;
            *(float4*)(dst + 8)  = v2;
            *(float4*)(dst + 12) = v3;
        }
        {
            const float2* src = XhT + (((size_t)((kyIdx << 4) + s_kx)) << 10)
                                    + (s_bb << 6) + (ic << 4);
            float2 xv[16];
            #pragma unroll
            for (int q = 0; q < 8; ++q)
                *(float4*)&xv[q << 1] = *(const float4*)(src + (q << 1));
            #pragma unroll
            for (int ii = 0; ii < 16; ++ii)
                Xl[s_kx][ii][s_bb] = xv[ii];
        }
        __syncthreads();

        #pragma unroll 4
        for (int ii = 0; ii < 16; ++ii) {
            float4 wr0 = *(const float4*)&Wr_l[ii][o8][kh << 3];
            float4 wr1 = *(const float4*)&Wr_l[ii][o8][(kh << 3) + 4];
            float4 wi0 = *(const float4*)&Wi_l[ii][o8][kh << 3];
            float4 wi1 = *(const float4*)&Wi_l[ii][o8][(kh << 3) + 4];
            const float wrv[8] = {wr0.x, wr0.y, wr0.z, wr0.w, wr1.x, wr1.y, wr1.z, wr1.w};
            const float wiv[8] = {wi0.x, wi0.y, wi0.z, wi0.w, wi1.x, wi1.y, wi1.z, wi1.w};
            #pragma unroll
            for (int j = 0; j < 8; ++j) {
                float2 xv = Xl[(kh << 3) + j][ii][b];
                acc[j].x = fmaf(xv.x, wrv[j], fmaf(-xv.y, wiv[j], acc[j].x));
                acc[j].y = fmaf(xv.x, wiv[j], fmaf( xv.y, wrv[j], acc[j].y));
            }
        }
    }

    const float sc = 1.52587890625e-05f;   // 1/65536
    const int o = (oc << 3) + o8;
    float2* sp = S + (((size_t)(b << 6) + o) << 9) + (kyIdx << 4) + (kh << 3);
    #pragma unroll
    for (int q = 0; q < 4; ++q) {
        float4 v = make_float4(acc[2 * q].x * sc, acc[2 * q].y * sc,
                               acc[2 * q + 1].x * sc, acc[2 * q + 1].y * sc);
        *(float4*)(sp + (q << 1)) = v;
    }
}

// ---------------- Pass 4: inverse DFT over h via MFMA ----------------
static __device__ __forceinline__ void sb_put(ushort* Sbh, ushort* Sbl,
                                              int rr, int cc, float vv) {
    ushort hh, ll; split2(vv, hh, ll);
    int idx = (cc << 6) + ((((rr) >> 3) ^ (cc & 7)) << 3) + (rr & 7);
    Sbh[idx] = hh; Sbl[idx] = ll;
}

__global__ __launch_bounds__(256, 3) void k_invh(const float2* __restrict__ S,
        const ushort* __restrict__ Th4h, const ushort* __restrict__ Th4l,
        ushort* __restrict__ Abh, ushort* __restrict__ Abl) {
    const int tid = threadIdx.x;
    const int lane = tid & 63;
    const int wv = tid >> 6;
    const int bid = blockIdx.x;
    const int bo = ((bid & 7) << 7) + (bid >> 3);     // XCD-chunked
    const int b = bo >> 6, o = bo & 63;
    const int l15 = lane & 15, l4 = lane >> 4;

    __shared__ ushort Sbh[2048];
    __shared__ ushort Sbl[2048];
    __shared__ float  Dl[256 * 33];

    {
        float4 sv = *(const float4*)(S + ((size_t)bo << 9) + (tid << 1));
        #pragma unroll
        for (int j = 0; j < 2; ++j) {
            int m = (tid << 1) + j;
            int ky = m >> 4, kx = m & 15;
            float sr = j ? sv.z : sv.x;
            float si = j ? sv.w : sv.y;
            float scl = kx ? 2.0f : 1.0f;
            sr *= scl; si *= scl;
            sb_put(Sbh, Sbl, ky,      kx,      sr);
            sb_put(Sbh, Sbl, 32 + ky, kx,     -si);
            sb_put(Sbh, Sbl, ky,      16 + kx, -si);
            sb_put(Sbh, Sbl, 32 + ky, 16 + kx, -sr);
        }
    }
    __syncthreads();

    f32x4 acc[4][2];
    #pragma unroll
    for (int i = 0; i < 4; ++i)
        #pragma unroll
        for (int nt = 0; nt < 2; ++nt)
            acc[i][nt] = (f32x4){0.f, 0.f, 0.f, 0.f};

    #pragma unroll
    for (int i = 0; i < 4; ++i) {
        const int hrow = (((wv << 2) + i) << 4) + l15;
        #pragma unroll
        for (int ks = 0; ks < 2; ++ks) {
            int aoff = (hrow << 6) + (ks << 5) + (l4 << 3);
            bf16x8 a_h = *(const bf16x8*)(Th4h + aoff);
            bf16x8 a_l = *(const bf16x8*)(Th4l + aoff);
            #pragma unroll
            for (int nt = 0; nt < 2; ++nt) {
                int col = (nt << 4) + l15;
                int oi = ((ks << 2) + l4) ^ (col & 7);
                bf16x8 b_h = *(const bf16x8*)(&Sbh[(col << 6) + (oi << 3)]);
                bf16x8 b_l = *(const bf16x8*)(&Sbl[(col << 6) + (oi << 3)]);
                acc[i][nt] = __builtin_amdgcn_mfma_f32_16x16x32_bf16(a_h, b_h, acc[i][nt], 0, 0, 0);
                acc[i][nt] = __builtin_amdgcn_mfma_f32_16x16x32_bf16(a_h, b_l, acc[i][nt], 0, 0, 0);
                acc[i][nt] = __builtin_amdgcn_mfma_f32_16x16x32_bf16(a_l, b_h, acc[i][nt], 0, 0, 0);
            }
        }
    }
    #pragma unroll
    for (int i = 0; i < 4; ++i)
        #pragma unroll
        for (int nt = 0; nt < 2; ++nt)
            #pragma unroll
            for (int r = 0; r < 4; ++r)
                Dl[((((wv << 2) + i) << 4) + (l4 << 2) + r) * 33 + (nt << 4) + l15]
                    = acc[i][nt][r];
    __syncthreads();

    {
        const int h = tid;
        ushort hi[32], lo[32];
        #pragma unroll
        for (int j = 0; j < 32; ++j)
            split2(Dl[h * 33 + j], hi[j], lo[j]);
        size_t base = (((size_t)((b << 8) + h)) << 11) + (o << 5);
        *(uint4*)(Abh + base)      = *(uint4*)&hi[0];
        *(uint4*)(Abh + base + 8)  = *(uint4*)&hi[8];
        *(uint4*)(Abh + base + 16) = *(uint4*)&hi[16];
        *(uint4*)(Abh + base + 24) = *(uint4*)&hi[24];
        *(uint4*)(Abl + base)      = *(uint4*)&lo[0];
        *(uint4*)(Abl + base + 8)  = *(uint4*)&lo[8];
        *(uint4*)(Abl + base + 16) = *(uint4*)&lo[16];
        *(uint4*)(Abl + base + 24) = *(uint4*)&lo[24];
    }
}

// ---------------- Pass 5: MFMA conv + inv-DFT-w + bias + GELU ----------------
// 4 blocks/CU (32 KB LDS); next-h x prefetch issued at TOP of iteration so HBM
// latency hides under Z-load + split8 + both barriers + MFMA.
__global__ __launch_bounds__(256, 4) void k_final(const float* __restrict__ x,
        const ushort* __restrict__ Wch, const ushort* __restrict__ Wcl,
        const ushort* __restrict__ Tgh, const ushort* __restrict__ Tgl,
        const ushort* __restrict__ Abh, const ushort* __restrict__ Abl,
        const float* __restrict__ bcv, float* __restrict__ out) {
    const int tid = threadIdx.x;
    const int lane = tid & 63;
    const int wv = tid >> 6;
    const int bid = blockIdx.x;
    const int gid = ((bid >> 5) << 3) | (bid & 7);
    const int wq  = (bid >> 3) & 3;
    const int b = gid >> 6, ht = gid & 63;
    const int w0 = wq << 6;

    __shared__ ushort Xh[64][128];
    __shared__ ushort Xl[64][128];

    const int l15 = lane & 15, l4 = lane >> 4;
    const int mt0 = (wv >> 1) << 1;
    const int nt0 = (wv & 1) << 1;
    const int wloc = tid & 63, cb0 = tid >> 6;

    const float* xb = x + ((size_t)b << 22) + ((size_t)(ht << 2) << 8) + w0 + wloc;

    float g[2][2][8];
    #pragma unroll
    for (int i = 0; i < 2; ++i) {
        const float* xpc = xb + ((size_t)(cb0 + (i << 2)) << 19);
        #pragma unroll
        for (int j = 0; j < 8; ++j) g[0][i][j] = xpc[(size_t)j << 16];
    }

    {
        size_t gg = ((size_t)(w0 + wloc) << 5) + (cb0 << 3);
        bf16x8 th = *(const bf16x8*)(Tgh + gg);
        bf16x8 tl = *(const bf16x8*)(Tgl + gg);
        int bidx = (8 + cb0) ^ (wloc & 7);
        *(bf16x8*)(&Xh[0][0] + (wloc << 7) + (bidx << 3)) = th;
        *(bf16x8*)(&Xl[0][0] + (wloc << 7) + (bidx << 3)) = tl;
    }

    bf16x8 aW[2][2][2];
    #pragma unroll
    for (int mi = 0; mi < 2; ++mi) {
        int o = ((mt0 + mi) << 4) + l15;
        #pragma unroll
        for (int ks = 0; ks < 2; ++ks) {
            size_t gg = ((size_t)o << 6) + (ks << 5) + (l4 << 3);
            aW[mi][ks][0] = *(const bf16x8*)(Wch + gg);
            aW[mi][ks][1] = *(const bf16x8*)(Wcl + gg);
        }
    }
    float bias[2][4];
    #pragma unroll
    for (int mi = 0; mi < 2; ++mi)
        #pragma unroll
        for (int r = 0; r < 4; ++r)
            bias[mi][r] = bcv[((mt0 + mi) << 4) + (l4 << 2) + r];

    #pragma unroll
    for (int hh = 0; hh < 4; ++hh) {
        const int h = (ht << 2) + hh;
        const int cur = hh & 1, nxt = cur ^ 1;

        // prefetch next h's x FIRST (g[nxt] is free here) — max latency overlap
        if (hh < 3) {
            #pragma unroll
            for (int i = 0; i < 2; ++i) {
                const float* xpc = xb + ((size_t)(cb0 + (i << 2)) << 19) + ((hh + 1) << 8);
                #pragma unroll
                for (int j = 0; j < 8; ++j) g[nxt][i][j] = xpc[(size_t)j << 16];
            }
        }

        bf16x8 zH[2], zL[2];
        #pragma unroll
        for (int mi = 0; mi < 2; ++mi) {
            int o = ((mt0 + mi) << 4) + l15;
            size_t gg = ((((size_t)((b << 8) + h) << 6) + o) << 5) + (l4 << 3);
            zH[mi] = *(const bf16x8*)(Abh + gg);
            zL[mi] = *(const bf16x8*)(Abl + gg);
        }

        bf16x8 hb[2], lb[2];
        split8(g[cur][0], hb[0], lb[0]);
        split8(g[cur][1], hb[1], lb[1]);

        __syncthreads();
        #pragma unroll
        for (int i = 0; i < 2; ++i) {
            int bidx = (cb0 + (i << 2)) ^ (wloc & 7);
            *(bf16x8*)(&Xh[0][0] + (wloc << 7) + (bidx << 3)) = hb[i];
            *(bf16x8*)(&Xl[0][0] + (wloc << 7) + (bidx << 3)) = lb[i];
        }
        __syncthreads();

        f32x4 acc[2][2];
        #pragma unroll
        for (int mi = 0; mi < 2; ++mi)
            #pragma unroll
            for (int ni = 0; ni < 2; ++ni)
                acc[mi][ni] = (f32x4){0.f, 0.f, 0.f, 0.f};

        #pragma unroll
        for (int ks = 0; ks < 3; ++ks) {
            bf16x8 bh[2], bl[2];
            #pragma unroll
            for (int ni = 0; ni < 2; ++ni) {
                int w = ((nt0 + ni) << 4) + l15;
                int bidx = ((ks << 2) + l4) ^ (w & 7);
                bh[ni] = *(const bf16x8*)(&Xh[0][0] + (w << 7) + (bidx << 3));
                bl[ni] = *(const bf16x8*)(&Xl[0][0] + (w << 7) + (bidx << 3));
            }
            #pragma unroll
            for (int mi = 0; mi < 2; ++mi) {
                bf16x8 ah_ = (ks < 2) ? aW[mi][ks][0] : zH[mi];
                bf16x8 al_ = (ks < 2) ? aW[mi][ks][1] : zL[mi];
                #pragma unroll
                for (int ni = 0; ni < 2; ++ni) {
                    acc[mi][ni] = __builtin_amdgcn_mfma_f32_16x16x32_bf16(ah_, bh[ni], acc[mi][ni], 0, 0, 0);
                    acc[mi][ni] = __builtin_amdgcn_mfma_f32_16x16x32_bf16(ah_, bl[ni], acc[mi][ni], 0, 0, 0);
                    acc[mi][ni] = __builtin_amdgcn_mfma_f32_16x16x32_bf16(al_, bh[ni], acc[mi][ni], 0, 0, 0);
                }
            }
        }

        #pragma unroll
        for (int mi = 0; mi < 2; ++mi) {
            #pragma unroll
            for (int ni = 0; ni < 2; ++ni) {
                int wg = w0 + ((nt0 + ni) << 4) + l15;
                #pragma unroll
                for (int r = 0; r < 4; ++r) {
                    int o = ((mt0 + mi) << 4) + (l4 << 2) + r;
                    float v = acc[mi][ni][r] + bias[mi][r];
                    out[((size_t)((b << 6) + o) << 16) + ((size_t)h << 8) + wg] = gelu_f(v);
                }
            }
        }
    }
}

extern "C" void kernel_launch(void* const* d_in, const int* in_sizes, int n_in,
                              void* d_out, int out_size, void* d_ws, size_t ws_size,
                              hipStream_t stream) {
    const float* x   = (const float*)d_in[0];
    const float* Wc  = (const float*)d_in[1];
    const float* bcv = (const float*)d_in[2];
    const float* w1r = (const float*)d_in[3];
    const float* w1i = (const float*)d_in[4];
    const float* w2r = (const float*)d_in[5];
    const float* w2i = (const float*)d_in[6];
    float* out = (float*)d_out;

    // Workspace (42.2 MB):
    //   [0, 33.5M):  Abh|Abl (pass4->5)
    //   [33.5M):     XhT 4M    [37.7M): S 4M    [41.9M+): tables
    char* wsb = (char*)d_ws;
    ushort* Abh  = (ushort*)wsb;
    ushort* Abl  = (ushort*)(wsb + 16777216);
    float2* XhT  = (float2*)(wsb + 33554432);
    float2* S    = (float2*)(wsb + 37748736);
    ushort* Wch  = (ushort*)(wsb + 41943040);
    ushort* Wcl  = (ushort*)(wsb + 41951232);
    ushort* Tgh  = (ushort*)(wsb + 41959424);
    ushort* Tgl  = (ushort*)(wsb + 41975808);
    ushort* Tkh  = (ushort*)(wsb + 41992192);
    ushort* Tkl  = (ushort*)(wsb + 42008576);
    ushort* Th2h = (ushort*)(wsb + 42024960);
    ushort* Th2l = (ushort*)(wsb + 42057728);
    ushort* Th4h = (ushort*)(wsb + 42090496);
    ushort* Th4l = (ushort*)(wsb + 42123264);

    k_prep <<< 208, 256, 0, stream>>>(Wc, Wch, Wcl, Tgh, Tgl, Tkh, Tkl,
                                      Th2h, Th2l, Th4h, Th4l);
    k_spec <<<1024, 256, 0, stream>>>(x, Tkh, Tkl, Th2h, Th2l, XhT);
    k_modes<<< 256, 256, 0, stream>>>(XhT, w1r, w1i, w2r, w2i, S);
    k_invh <<<1024, 256, 0, stream>>>(S, Th4h, Th4l, Abh, Abl);
    k_final<<<4096, 256, 0, stream>>>(x, Wch, Wcl, Tgh, Tgl, Abh, Abl, bcv, out);
}

// Round 9
// 279.185 us; speedup vs baseline: 1.6710x; 1.6710x over previous
//
#include <hip/hip_runtime.h>
#include <hip/hip_bf16.h>
#include <math.h>

#define TWO_PI_256 0.024543692606170259678f  // 2*pi/256

typedef __attribute__((ext_vector_type(8))) short bf16x8;
typedef __attribute__((ext_vector_type(4))) float f32x4;

static __device__ __forceinline__ ushort bf16_rn(float a) {
    union { float f; unsigned int u; } v; v.f = a;
    unsigned int r = v.u + 0x7FFFu + ((v.u >> 16) & 1u);
    return (ushort)(r >> 16);
}
static __device__ __forceinline__ float bf16_to_f(ushort h) {
    union { unsigned int u; float f; } v; v.u = ((unsigned int)h) << 16;
    return v.f;
}
static __device__ __forceinline__ void split2(float a, ushort& hi, ushort& lo) {
    ushort h = bf16_rn(a);
    hi = h;
    lo = bf16_rn(a - bf16_to_f(h));
}

// hw cvt_pk path: 8 floats -> bf16-hi x8 + bf16-lo x8
static __device__ __forceinline__ void split8(const float* v, bf16x8& hi8, bf16x8& lo8) {
    union { ushort u[8]; bf16x8 v8; } H, L;
    #pragma unroll
    for (int j = 0; j < 8; j += 2) {
        __hip_bfloat162 hb = __float22bfloat162_rn(make_float2(v[j], v[j + 1]));
        ushort2 hu = *reinterpret_cast<ushort2*>(&hb);
        float fx = __uint_as_float((unsigned int)hu.x << 16);
        float fy = __uint_as_float((unsigned int)hu.y << 16);
        __hip_bfloat162 lb = __float22bfloat162_rn(make_float2(v[j] - fx, v[j + 1] - fy));
        ushort2 lu = *reinterpret_cast<ushort2*>(&lb);
        H.u[j] = hu.x; H.u[j + 1] = hu.y;
        L.u[j] = lu.x; L.u[j + 1] = lu.y;
    }
    hi8 = H.v8; lo8 = L.v8;
}

// branchless tanh-form GELU (max |delta| vs exact-erf gelu ~5e-4)
static __device__ __forceinline__ float gelu_f(float v) {
    float z = v * fmaf(v * v, 0.10294321f, 2.3022082f);   // 2u/ln2
    float e = __builtin_amdgcn_exp2f(z);
    return v - v * __builtin_amdgcn_rcpf(e + 1.0f);
}

// ---------------- Pass 0: bf16-split tables ----------------
__global__ __launch_bounds__(256) void k_prep(const float* __restrict__ Wc,
        ushort* __restrict__ Wch, ushort* __restrict__ Wcl,
        ushort* __restrict__ Tgh, ushort* __restrict__ Tgl,
        ushort* __restrict__ Tkh, ushort* __restrict__ Tkl,
        ushort* __restrict__ Th2h, ushort* __restrict__ Th2l,
        ushort* __restrict__ Th4h, ushort* __restrict__ Th4l) {
    int g = blockIdx.x * 256 + threadIdx.x;
    if (g < 4096) {
        ushort h, l; split2(Wc[g], h, l);
        Wch[g] = h; Wcl[g] = l;
    }
    int t = g - 4096;
    if (t >= 0 && t < 8192) {
        int w = t >> 5, kz = t & 31, kx = kz & 15;
        int ph = (w * kx) & 255;
        float s, c; sincosf((float)ph * TWO_PI_256, &s, &c);
        float val = (kz < 16) ? c : s;
        ushort h, l; split2(val, h, l);
        Tgh[t] = h; Tgl[t] = l;
    }
    int t2 = g - 12288;
    if (t2 >= 0 && t2 < 8192) {
        int j = t2 >> 8, w = t2 & 255, kx = j & 15;
        int ph = (w * kx) & 255;
        float s, c; sincosf((float)ph * TWO_PI_256, &s, &c);
        float val = (j < 16) ? c : s;
        ushort h, l; split2(val, h, l);
        Tkh[t2] = h; Tkl[t2] = l;
    }
    int t3 = g - 20480;
    if (t3 >= 0 && t3 < 16384) {
        int row = t3 >> 8, h = t3 & 255;
        int ky = row & 31;
        int phys = (ky < 16) ? ky : (224 + ky);
        int ph = (phys * h) & 255;
        float s, c; sincosf((float)ph * TWO_PI_256, &s, &c);
        float val = (row < 32) ? c : s;
        ushort hh, ll; split2(val, hh, ll);
        Th2h[t3] = hh; Th2l[t3] = ll;
    }
    int t4 = g - 36864;
    if (t4 >= 0 && t4 < 16384) {
        int h = t4 >> 6, col = t4 & 63;
        int ky = col & 31;
        int phys = (ky < 16) ? ky : (224 + ky);
        int ph = (phys * h) & 255;
        float s, c; sincosf((float)ph * TWO_PI_256, &s, &c);
        float val = (col < 32) ? c : s;
        ushort hh, ll; split2(val, hh, ll);
        Th4h[t4] = hh; Th4l[t4] = ll;
    }
}

// ---------------- Pass 1+2 fused: w-DFT then h-DFT, one block per plane ----------------
__global__ __launch_bounds__(256) void k_spec(const float* __restrict__ x,
        const ushort* __restrict__ Tkh, const ushort* __restrict__ Tkl,
        const ushort* __restrict__ Th2h, const ushort* __restrict__ Th2l,
        float2* __restrict__ XhT) {
    const int tid = threadIdx.x;
    const int lane = tid & 63;
    const int wv = tid >> 6;
    const int bid = blockIdx.x;
    const int bc = ((bid & 7) << 7) + (bid >> 3);     // XCD-chunked (bijective, 1024 = 8*128)
    const int l15 = lane & 15, l4 = lane >> 4;
    const int mt = wv >> 1, nt = wv & 1;

    __shared__ ushort Ah[32 * 256];    // chunk x bf16-hi, octet^(h&7) swizzled
    __shared__ ushort Al[32 * 256];
    __shared__ ushort Xwh[32 * 256];   // [col][h] bf16-hi, h-octet^(col&7) swizzled
    __shared__ ushort Xwl[32 * 256];
    __shared__ float  Dl[64 * 33];

    const float* xp = x + ((size_t)bc << 16);

    const int rbase = ((mt << 4) + l15) << 8;          // A row base (ushorts)
    const int rs = ((mt << 4) + l15) & 7;
    const int jrow = (nt << 4) + l15;                  // Tk row / Xw col

#define LDCH(pf, c) { \
    _Pragma("unroll") \
    for (int i_ = 0; i_ < 4; ++i_) { \
        int f8_ = tid + (i_ << 8); \
        int hh_ = f8_ >> 5, oct_ = f8_ & 31; \
        const float* p_ = xp + (((c) << 5) + hh_) * 256 + (oct_ << 3); \
        *(float4*)&pf[i_ * 8]     = *(const float4*)(p_); \
        *(float4*)&pf[i_ * 8 + 4] = *(const float4*)(p_ + 4); \
    } }

#define STAGE_A(pf) { \
    _Pragma("unroll") \
    for (int i_ = 0; i_ < 4; ++i_) { \
        int f8_ = tid + (i_ << 8); \
        int hh_ = f8_ >> 5, oct_ = f8_ & 31; \
        bf16x8 hi8_, lo8_; \
        split8(&pf[i_ * 8], hi8_, lo8_); \
        int bx_ = oct_ ^ (hh_ & 7); \
        *(bf16x8*)(&Ah[(hh_ << 8) + (bx_ << 3)]) = hi8_; \
        *(bf16x8*)(&Al[(hh_ << 8) + (bx_ << 3)]) = lo8_; \
    } }

    float pfA[32], pfB[32];
    LDCH(pfA, 0);
    LDCH(pfB, 1);

    #pragma unroll
    for (int c = 0; c < 8; ++c) {
        __syncthreads();                 // prior chunk's A reads complete
        if (c & 1) { STAGE_A(pfB); } else { STAGE_A(pfA); }
        __syncthreads();
        if (c + 2 < 8) {                 // refill the just-consumed buffer
            if (c & 1) { LDCH(pfB, c + 2); } else { LDCH(pfA, c + 2); }
        }

        f32x4 acc = {0.f, 0.f, 0.f, 0.f};
        #pragma unroll
        for (int ks = 0; ks < 8; ++ks) {
            int boff = ((((ks << 2) + l4) ^ rs) << 3);
            bf16x8 a_h = *(const bf16x8*)(&Ah[rbase + boff]);
            bf16x8 a_l = *(const bf16x8*)(&Al[rbase + boff]);
            int toff = (jrow << 8) + (ks << 5) + (l4 << 3);
            bf16x8 b_h = *(const bf16x8*)(Tkh + toff);
            bf16x8 b_l = *(const bf16x8*)(Tkl + toff);
            acc = __builtin_amdgcn_mfma_f32_16x16x32_bf16(a_h, b_h, acc, 0, 0, 0);
            acc = __builtin_amdgcn_mfma_f32_16x16x32_bf16(a_h, b_l, acc, 0, 0, 0);
            acc = __builtin_amdgcn_mfma_f32_16x16x32_bf16(a_l, b_h, acc, 0, 0, 0);
        }
        // D: col=jrow, h = c*32 + mt*16 + l4*4 + r. nt=1 rows are sin -> Im = -acc.
        ushort hi4[4], lo4[4];
        #pragma unroll
        for (int r = 0; r < 4; ++r) {
            float v = nt ? -acc[r] : acc[r];
            split2(v, hi4[r], lo4[r]);
        }
        int habs = (c << 5) + (mt << 4) + (l4 << 2);
        int op = (habs >> 3) ^ (jrow & 7);
        int addr = (jrow << 8) + (op << 3) + (habs & 7);
        *(ushort4*)(&Xwh[addr]) = *(ushort4*)hi4;
        *(ushort4*)(&Xwl[addr]) = *(ushort4*)lo4;
    }
    __syncthreads();                     // Xw writes visible

    // ---- h-DFT: D2[64 ky'][32 col] = Th2 * Xw ----
    f32x4 acc2[2];
    acc2[0] = (f32x4){0.f, 0.f, 0.f, 0.f};
    acc2[1] = (f32x4){0.f, 0.f, 0.f, 0.f};
    const int arow = (wv << 4) + l15;
    #pragma unroll
    for (int ks = 0; ks < 8; ++ks) {
        int aoff = (arow << 8) + (ks << 5) + (l4 << 3);
        bf16x8 a_h = *(const bf16x8*)(Th2h + aoff);
        bf16x8 a_l = *(const bf16x8*)(Th2l + aoff);
        #pragma unroll
        for (int nt2 = 0; nt2 < 2; ++nt2) {
            int col = (nt2 << 4) + l15;
            int oi = ((ks << 2) + l4) ^ (col & 7);
            bf16x8 b_h = *(const bf16x8*)(&Xwh[(col << 8) + (oi << 3)]);
            bf16x8 b_l = *(const bf16x8*)(&Xwl[(col << 8) + (oi << 3)]);
            acc2[nt2] = __builtin_amdgcn_mfma_f32_16x16x32_bf16(a_h, b_h, acc2[nt2], 0, 0, 0);
            acc2[nt2] = __builtin_amdgcn_mfma_f32_16x16x32_bf16(a_h, b_l, acc2[nt2], 0, 0, 0);
            acc2[nt2] = __builtin_amdgcn_mfma_f32_16x16x32_bf16(a_l, b_h, acc2[nt2], 0, 0, 0);
        }
    }
    #pragma unroll
    for (int nt2 = 0; nt2 < 2; ++nt2)
        #pragma unroll
        for (int r = 0; r < 4; ++r)
            Dl[((wv << 4) + (l4 << 2) + r) * 33 + (nt2 << 4) + l15] = acc2[nt2][r];
    __syncthreads();

    #pragma unroll
    for (int q = 0; q < 2; ++q) {
        int m = tid + (q << 8);
        int ky = m >> 4, kx = m & 15;
        float re = Dl[ky * 33 + kx] + Dl[(32 + ky) * 33 + 16 + kx];
        float im = Dl[ky * 33 + 16 + kx] - Dl[(32 + ky) * 33 + kx];
        XhT[((size_t)m << 10) + bc] = make_float2(re, im);
    }
#undef LDCH
#undef STAGE_A
}

// ---------------- Pass 3: channel mix, coalesced-weight version ----------------
__global__ __launch_bounds__(256) void k_modes(const float2* __restrict__ XhT,
        const float* __restrict__ w1r, const float* __restrict__ w1i,
        const float* __restrict__ w2r, const float* __restrict__ w2i,
        float2* __restrict__ S) {
    const int tid = threadIdx.x;
    const int kyIdx = blockIdx.x >> 3;
    const int oc    = blockIdx.x & 7;
    const int xy0   = (kyIdx & 15) << 4;
    const float* __restrict__ wr = (kyIdx < 16) ? w1r : w2r;
    const float* __restrict__ wi = (kyIdx < 16) ? w1i : w2i;

    __shared__ float2 Xl[16][16][17];
    __shared__ float  Wr_l[16][8][20];
    __shared__ float  Wi_l[16][8][20];

    const int b  = tid >> 4;
    const int o8 = (tid >> 1) & 7;
    const int kh = tid & 1;

    const int s_ii = tid >> 4, s_oj = (tid >> 1) & 7, s_part = tid & 1;
    const int s_kx = tid >> 4, s_bb = tid & 15;

    float2 acc[8];
    #pragma unroll
    for (int j = 0; j < 8; ++j) acc[j] = make_float2(0.f, 0.f);

    for (int ic = 0; ic < 4; ++ic) {
        if (ic) __syncthreads();
        {
            const float* src = s_part ? wi : wr;
            size_t off = ((size_t)(((ic << 4) + s_ii) * 64 + (oc << 3) + s_oj) << 8) + xy0;
            float4 v0 = *(const float4*)(src + off);
            float4 v1 = *(const float4*)(src + off + 4);
            float4 v2 = *(const float4*)(src + off + 8);
            float4 v3 = *(const float4*)(src + off + 12);
            float* dst = s_part ? &Wi_l[s_ii][s_oj][0] : &Wr_l[s_ii][s_oj][0];
            *(float4*)(dst)      = v0;
            *(float4*)(dst + 4)  = v1;
            *(float4*)(dst + 8)  = v2;
            *(float4*)(dst + 12) = v3;
        }
        {
            const float2* src = XhT + (((size_t)((kyIdx << 4) + s_kx)) << 10)
                                    + (s_bb << 6) + (ic << 4);
            float2 xv[16];
            #pragma unroll
            for (int q = 0; q < 8; ++q)
                *(float4*)&xv[q << 1] = *(const float4*)(src + (q << 1));
            #pragma unroll
            for (int ii = 0; ii < 16; ++ii)
                Xl[s_kx][ii][s_bb] = xv[ii];
        }
        __syncthreads();

        #pragma unroll 4
        for (int ii = 0; ii < 16; ++ii) {
            float4 wr0 = *(const float4*)&Wr_l[ii][o8][kh << 3];
            float4 wr1 = *(const float4*)&Wr_l[ii][o8][(kh << 3) + 4];
            float4 wi0 = *(const float4*)&Wi_l[ii][o8][kh << 3];
            float4 wi1 = *(const float4*)&Wi_l[ii][o8][(kh << 3) + 4];
            const float wrv[8] = {wr0.x, wr0.y, wr0.z, wr0.w, wr1.x, wr1.y, wr1.z, wr1.w};
            const float wiv[8] = {wi0.x, wi0.y, wi0.z, wi0.w, wi1.x, wi1.y, wi1.z, wi1.w};
            #pragma unroll
            for (int j = 0; j < 8; ++j) {
                float2 xv = Xl[(kh << 3) + j][ii][b];
                acc[j].x = fmaf(xv.x, wrv[j], fmaf(-xv.y, wiv[j], acc[j].x));
                acc[j].y = fmaf(xv.x, wiv[j], fmaf( xv.y, wrv[j], acc[j].y));
            }
        }
    }

    const float sc = 1.52587890625e-05f;   // 1/65536
    const int o = (oc << 3) + o8;
    float2* sp = S + (((size_t)(b << 6) + o) << 9) + (kyIdx << 4) + (kh << 3);
    #pragma unroll
    for (int q = 0; q < 4; ++q) {
        float4 v = make_float4(acc[2 * q].x * sc, acc[2 * q].y * sc,
                               acc[2 * q + 1].x * sc, acc[2 * q + 1].y * sc);
        *(float4*)(sp + (q << 1)) = v;
    }
}

// ---------------- Pass 4: inverse DFT over h via MFMA ----------------
static __device__ __forceinline__ void sb_put(ushort* Sbh, ushort* Sbl,
                                              int rr, int cc, float vv) {
    ushort hh, ll; split2(vv, hh, ll);
    int idx = (cc << 6) + ((((rr) >> 3) ^ (cc & 7)) << 3) + (rr & 7);
    Sbh[idx] = hh; Sbl[idx] = ll;
}

__global__ __launch_bounds__(256) void k_invh(const float2* __restrict__ S,
        const ushort* __restrict__ Th4h, const ushort* __restrict__ Th4l,
        ushort* __restrict__ Abh, ushort* __restrict__ Abl) {
    const int tid = threadIdx.x;
    const int lane = tid & 63;
    const int wv = tid >> 6;
    const int bid = blockIdx.x;
    const int bo = ((bid & 7) << 7) + (bid >> 3);     // XCD-chunked
    const int b = bo >> 6, o = bo & 63;
    const int l15 = lane & 15, l4 = lane >> 4;

    __shared__ ushort Sbh[2048];
    __shared__ ushort Sbl[2048];
    __shared__ float  Dl[256 * 33];

    {
        float4 sv = *(const float4*)(S + ((size_t)bo << 9) + (tid << 1));
        #pragma unroll
        for (int j = 0; j < 2; ++j) {
            int m = (tid << 1) + j;
            int ky = m >> 4, kx = m & 15;
            float sr = j ? sv.z : sv.x;
            float si = j ? sv.w : sv.y;
            float scl = kx ? 2.0f : 1.0f;
            sr *= scl; si *= scl;
            sb_put(Sbh, Sbl, ky,      kx,      sr);
            sb_put(Sbh, Sbl, 32 + ky, kx,     -si);
            sb_put(Sbh, Sbl, ky,      16 + kx, -si);
            sb_put(Sbh, Sbl, 32 + ky, 16 + kx, -sr);
        }
    }
    __syncthreads();

    f32x4 acc[4][2];
    #pragma unroll
    for (int i = 0; i < 4; ++i)
        #pragma unroll
        for (int nt = 0; nt < 2; ++nt)
            acc[i][nt] = (f32x4){0.f, 0.f, 0.f, 0.f};

    #pragma unroll
    for (int i = 0; i < 4; ++i) {
        const int hrow = (((wv << 2) + i) << 4) + l15;
        #pragma unroll
        for (int ks = 0; ks < 2; ++ks) {
            int aoff = (hrow << 6) + (ks << 5) + (l4 << 3);
            bf16x8 a_h = *(const bf16x8*)(Th4h + aoff);
            bf16x8 a_l = *(const bf16x8*)(Th4l + aoff);
            #pragma unroll
            for (int nt = 0; nt < 2; ++nt) {
                int col = (nt << 4) + l15;
                int oi = ((ks << 2) + l4) ^ (col & 7);
                bf16x8 b_h = *(const bf16x8*)(&Sbh[(col << 6) + (oi << 3)]);
                bf16x8 b_l = *(const bf16x8*)(&Sbl[(col << 6) + (oi << 3)]);
                acc[i][nt] = __builtin_amdgcn_mfma_f32_16x16x32_bf16(a_h, b_h, acc[i][nt], 0, 0, 0);
                acc[i][nt] = __builtin_amdgcn_mfma_f32_16x16x32_bf16(a_h, b_l, acc[i][nt], 0, 0, 0);
                acc[i][nt] = __builtin_amdgcn_mfma_f32_16x16x32_bf16(a_l, b_h, acc[i][nt], 0, 0, 0);
            }
        }
    }
    #pragma unroll
    for (int i = 0; i < 4; ++i)
        #pragma unroll
        for (int nt = 0; nt < 2; ++nt)
            #pragma unroll
            for (int r = 0; r < 4; ++r)
                Dl[((((wv << 2) + i) << 4) + (l4 << 2) + r) * 33 + (nt << 4) + l15]
                    = acc[i][nt][r];
    __syncthreads();

    {
        const int h = tid;
        ushort hi[32], lo[32];
        #pragma unroll
        for (int j = 0; j < 32; ++j)
            split2(Dl[h * 33 + j], hi[j], lo[j]);
        size_t base = (((size_t)((b << 8) + h)) << 11) + (o << 5);
        *(uint4*)(Abh + base)      = *(uint4*)&hi[0];
        *(uint4*)(Abh + base + 8)  = *(uint4*)&hi[8];
        *(uint4*)(Abh + base + 16) = *(uint4*)&hi[16];
        *(uint4*)(Abh + base + 24) = *(uint4*)&hi[24];
        *(uint4*)(Abl + base)      = *(uint4*)&lo[0];
        *(uint4*)(Abl + base + 8)  = *(uint4*)&lo[8];
        *(uint4*)(Abl + base + 16) = *(uint4*)&lo[16];
        *(uint4*)(Abl + base + 24) = *(uint4*)&lo[24];
    }
}

// ---------------- Pass 5: MFMA conv + inv-DFT-w + bias + GELU ----------------
// r7 schedule restored: 3 blocks/CU; next-h x prefetch issued AFTER the stage
// barriers so its vmcnt drain lands at the NEXT iteration's barrier (full
// MFMA+epilogue+Z-load overlap window). r8's prefetch-at-top + 4 blk/CU
// regressed 2.3x (barrier vmcnt(0) drain + L2 thrash; FETCH 432MB WRITE 599MB).
__global__ __launch_bounds__(256, 3) void k_final(const float* __restrict__ x,
        const ushort* __restrict__ Wch, const ushort* __restrict__ Wcl,
        const ushort* __restrict__ Tgh, const ushort* __restrict__ Tgl,
        const ushort* __restrict__ Abh, const ushort* __restrict__ Abl,
        const float* __restrict__ bcv, float* __restrict__ out) {
    const int tid = threadIdx.x;
    const int lane = tid & 63;
    const int wv = tid >> 6;
    const int bid = blockIdx.x;
    const int gid = ((bid >> 5) << 3) | (bid & 7);
    const int wq  = (bid >> 3) & 3;
    const int b = gid >> 6, ht = gid & 63;
    const int w0 = wq << 6;

    __shared__ ushort Xh[64][128];
    __shared__ ushort Xl[64][128];

    const int l15 = lane & 15, l4 = lane >> 4;
    const int mt0 = (wv >> 1) << 1;
    const int nt0 = (wv & 1) << 1;
    const int wloc = tid & 63, cb0 = tid >> 6;

    const float* xb = x + ((size_t)b << 22) + ((size_t)(ht << 2) << 8) + w0 + wloc;

    float g[2][2][8];
    #pragma unroll
    for (int i = 0; i < 2; ++i) {
        const float* xpc = xb + ((size_t)(cb0 + (i << 2)) << 19);
        #pragma unroll
        for (int j = 0; j < 8; ++j) g[0][i][j] = xpc[(size_t)j << 16];
    }

    {
        size_t gg = ((size_t)(w0 + wloc) << 5) + (cb0 << 3);
        bf16x8 th = *(const bf16x8*)(Tgh + gg);
        bf16x8 tl = *(const bf16x8*)(Tgl + gg);
        int bidx = (8 + cb0) ^ (wloc & 7);
        *(bf16x8*)(&Xh[0][0] + (wloc << 7) + (bidx << 3)) = th;
        *(bf16x8*)(&Xl[0][0] + (wloc << 7) + (bidx << 3)) = tl;
    }

    bf16x8 aW[2][2][2];
    #pragma unroll
    for (int mi = 0; mi < 2; ++mi) {
        int o = ((mt0 + mi) << 4) + l15;
        #pragma unroll
        for (int ks = 0; ks < 2; ++ks) {
            size_t gg = ((size_t)o << 6) + (ks << 5) + (l4 << 3);
            aW[mi][ks][0] = *(const bf16x8*)(Wch + gg);
            aW[mi][ks][1] = *(const bf16x8*)(Wcl + gg);
        }
    }
    float bias[2][4];
    #pragma unroll
    for (int mi = 0; mi < 2; ++mi)
        #pragma unroll
        for (int r = 0; r < 4; ++r)
            bias[mi][r] = bcv[((mt0 + mi) << 4) + (l4 << 2) + r];

    #pragma unroll
    for (int hh = 0; hh < 4; ++hh) {
        const int h = (ht << 2) + hh;
        const int cur = hh & 1, nxt = cur ^ 1;

        bf16x8 zH[2], zL[2];
        #pragma unroll
        for (int mi = 0; mi < 2; ++mi) {
            int o = ((mt0 + mi) << 4) + l15;
            size_t gg = ((((size_t)((b << 8) + h) << 6) + o) << 5) + (l4 << 3);
            zH[mi] = *(const bf16x8*)(Abh + gg);
            zL[mi] = *(const bf16x8*)(Abl + gg);
        }

        bf16x8 hb[2], lb[2];
        split8(g[cur][0], hb[0], lb[0]);
        split8(g[cur][1], hb[1], lb[1]);

        __syncthreads();
        #pragma unroll
        for (int i = 0; i < 2; ++i) {
            int bidx = (cb0 + (i << 2)) ^ (wloc & 7);
            *(bf16x8*)(&Xh[0][0] + (wloc << 7) + (bidx << 3)) = hb[i];
            *(bf16x8*)(&Xl[0][0] + (wloc << 7) + (bidx << 3)) = lb[i];
        }
        __syncthreads();

        // prefetch next h's x here: loads stay in flight through MFMA+epilogue
        // and the next iteration's Z-loads; drained at the NEXT barrier.
        if (hh < 3) {
            #pragma unroll
            for (int i = 0; i < 2; ++i) {
                const float* xpc = xb + ((size_t)(cb0 + (i << 2)) << 19) + ((hh + 1) << 8);
                #pragma unroll
                for (int j = 0; j < 8; ++j) g[nxt][i][j] = xpc[(size_t)j << 16];
            }
        }

        f32x4 acc[2][2];
        #pragma unroll
        for (int mi = 0; mi < 2; ++mi)
            #pragma unroll
            for (int ni = 0; ni < 2; ++ni)
                acc[mi][ni] = (f32x4){0.f, 0.f, 0.f, 0.f};

        #pragma unroll
        for (int ks = 0; ks < 3; ++ks) {
            bf16x8 bh[2], bl[2];
            #pragma unroll
            for (int ni = 0; ni < 2; ++ni) {
                int w = ((nt0 + ni) << 4) + l15;
                int bidx = ((ks << 2) + l4) ^ (w & 7);
                bh[ni] = *(const bf16x8*)(&Xh[0][0] + (w << 7) + (bidx << 3));
                bl[ni] = *(const bf16x8*)(&Xl[0][0] + (w << 7) + (bidx << 3));
            }
            #pragma unroll
            for (int mi = 0; mi < 2; ++mi) {
                bf16x8 ah_ = (ks < 2) ? aW[mi][ks][0] : zH[mi];
                bf16x8 al_ = (ks < 2) ? aW[mi][ks][1] : zL[mi];
                #pragma unroll
                for (int ni = 0; ni < 2; ++ni) {
                    acc[mi][ni] = __builtin_amdgcn_mfma_f32_16x16x32_bf16(ah_, bh[ni], acc[mi][ni], 0, 0, 0);
                    acc[mi][ni] = __builtin_amdgcn_mfma_f32_16x16x32_bf16(ah_, bl[ni], acc[mi][ni], 0, 0, 0);
                    acc[mi][ni] = __builtin_amdgcn_mfma_f32_16x16x32_bf16(al_, bh[ni], acc[mi][ni], 0, 0, 0);
                }
            }
        }

        #pragma unroll
        for (int mi = 0; mi < 2; ++mi) {
            #pragma unroll
            for (int ni = 0; ni < 2; ++ni) {
                int wg = w0 + ((nt0 + ni) << 4) + l15;
                #pragma unroll
                for (int r = 0; r < 4; ++r) {
                    int o = ((mt0 + mi) << 4) + (l4 << 2) + r;
                    float v = acc[mi][ni][r] + bias[mi][r];
                    out[((size_t)((b << 6) + o) << 16) + ((size_t)h << 8) + wg] = gelu_f(v);
                }
            }
        }
    }
}

extern "C" void kernel_launch(void* const* d_in, const int* in_sizes, int n_in,
                              void* d_out, int out_size, void* d_ws, size_t ws_size,
                              hipStream_t stream) {
    const float* x   = (const float*)d_in[0];
    const float* Wc  = (const float*)d_in[1];
    const float* bcv = (const float*)d_in[2];
    const float* w1r = (const float*)d_in[3];
    const float* w1i = (const float*)d_in[4];
    const float* w2r = (const float*)d_in[5];
    const float* w2i = (const float*)d_in[6];
    float* out = (float*)d_out;

    // Workspace (42.2 MB):
    //   [0, 33.5M):  Abh|Abl (pass4->5)
    //   [33.5M):     XhT 4M    [37.7M): S 4M    [41.9M+): tables
    char* wsb = (char*)d_ws;
    ushort* Abh  = (ushort*)wsb;
    ushort* Abl  = (ushort*)(wsb + 16777216);
    float2* XhT  = (float2*)(wsb + 33554432);
    float2* S    = (float2*)(wsb + 37748736);
    ushort* Wch  = (ushort*)(wsb + 41943040);
    ushort* Wcl  = (ushort*)(wsb + 41951232);
    ushort* Tgh  = (ushort*)(wsb + 41959424);
    ushort* Tgl  = (ushort*)(wsb + 41975808);
    ushort* Tkh  = (ushort*)(wsb + 41992192);
    ushort* Tkl  = (ushort*)(wsb + 42008576);
    ushort* Th2h = (ushort*)(wsb + 42024960);
    ushort* Th2l = (ushort*)(wsb + 42057728);
    ushort* Th4h = (ushort*)(wsb + 42090496);
    ushort* Th4l = (ushort*)(wsb + 42123264);

    k_prep <<< 208, 256, 0, stream>>>(Wc, Wch, Wcl, Tgh, Tgl, Tkh, Tkl,
                                      Th2h, Th2l, Th4h, Th4l);
    k_spec <<<1024, 256, 0, stream>>>(x, Tkh, Tkl, Th2h, Th2l, XhT);
    k_modes<<< 256, 256, 0, stream>>>(XhT, w1r, w1i, w2r, w2i, S);
    k_invh <<<1024, 256, 0, stream>>>(S, Th4h, Th4l, Abh, Abl);
    k_final<<<4096, 256, 0, stream>>>(x, Wch, Wcl, Tgh, Tgl, Abh, Abl, bcv, out);
}

// Round 10
// 271.736 us; speedup vs baseline: 1.7168x; 1.0274x over previous
//
#include <hip/hip_runtime.h>
#include <hip/hip_bf16.h>
#include <math.h>

#define TWO_PI_256 0.024543692606170259678f  // 2*pi/256

typedef __attribute__((ext_vector_type(8))) short bf16x8;
typedef __attribute__((ext_vector_type(4))) float f32x4;

static __device__ __forceinline__ ushort bf16_rn(float a) {
    union { float f; unsigned int u; } v; v.f = a;
    unsigned int r = v.u + 0x7FFFu + ((v.u >> 16) & 1u);
    return (ushort)(r >> 16);
}
static __device__ __forceinline__ float bf16_to_f(ushort h) {
    union { unsigned int u; float f; } v; v.u = ((unsigned int)h) << 16;
    return v.f;
}
static __device__ __forceinline__ void split2(float a, ushort& hi, ushort& lo) {
    ushort h = bf16_rn(a);
    hi = h;
    lo = bf16_rn(a - bf16_to_f(h));
}

// hw cvt_pk path: 8 floats -> bf16-hi x8 + bf16-lo x8
static __device__ __forceinline__ void split8(const float* v, bf16x8& hi8, bf16x8& lo8) {
    union { ushort u[8]; bf16x8 v8; } H, L;
    #pragma unroll
    for (int j = 0; j < 8; j += 2) {
        __hip_bfloat162 hb = __float22bfloat162_rn(make_float2(v[j], v[j + 1]));
        ushort2 hu = *reinterpret_cast<ushort2*>(&hb);
        float fx = __uint_as_float((unsigned int)hu.x << 16);
        float fy = __uint_as_float((unsigned int)hu.y << 16);
        __hip_bfloat162 lb = __float22bfloat162_rn(make_float2(v[j] - fx, v[j + 1] - fy));
        ushort2 lu = *reinterpret_cast<ushort2*>(&lb);
        H.u[j] = hu.x; H.u[j + 1] = hu.y;
        L.u[j] = lu.x; L.u[j + 1] = lu.y;
    }
    hi8 = H.v8; lo8 = L.v8;
}

// hi-only: 8 floats -> bf16 x8 (4 cvt_pk)
static __device__ __forceinline__ void cvt8_hi(const float* v, bf16x8& hi8) {
    union { ushort u[8]; bf16x8 v8; } H;
    #pragma unroll
    for (int j = 0; j < 8; j += 2) {
        __hip_bfloat162 hb = __float22bfloat162_rn(make_float2(v[j], v[j + 1]));
        ushort2 hu = *reinterpret_cast<ushort2*>(&hb);
        H.u[j] = hu.x; H.u[j + 1] = hu.y;
    }
    hi8 = H.v8;
}

// branchless tanh-form GELU (max |delta| vs exact-erf gelu ~5e-4)
static __device__ __forceinline__ float gelu_f(float v) {
    float z = v * fmaf(v * v, 0.10294321f, 2.3022082f);   // 2u/ln2
    float e = __builtin_amdgcn_exp2f(z);
    return v - v * __builtin_amdgcn_rcpf(e + 1.0f);
}

// ---------------- Pass 0: bf16-split tables ----------------
__global__ __launch_bounds__(256) void k_prep(const float* __restrict__ Wc,
        ushort* __restrict__ Wch, ushort* __restrict__ Wcl,
        ushort* __restrict__ Tgh, ushort* __restrict__ Tgl,
        ushort* __restrict__ Tkh, ushort* __restrict__ Tkl,
        ushort* __restrict__ Th2h, ushort* __restrict__ Th2l,
        ushort* __restrict__ Th4h, ushort* __restrict__ Th4l) {
    int g = blockIdx.x * 256 + threadIdx.x;
    if (g < 4096) {
        ushort h, l; split2(Wc[g], h, l);
        Wch[g] = h; Wcl[g] = l;
    }
    int t = g - 4096;
    if (t >= 0 && t < 8192) {
        int w = t >> 5, kz = t & 31, kx = kz & 15;
        int ph = (w * kx) & 255;
        float s, c; sincosf((float)ph * TWO_PI_256, &s, &c);
        float val = (kz < 16) ? c : s;
        ushort h, l; split2(val, h, l);
        Tgh[t] = h; Tgl[t] = l;
    }
    int t2 = g - 12288;
    if (t2 >= 0 && t2 < 8192) {
        int j = t2 >> 8, w = t2 & 255, kx = j & 15;
        int ph = (w * kx) & 255;
        float s, c; sincosf((float)ph * TWO_PI_256, &s, &c);
        float val = (j < 16) ? c : s;
        ushort h, l; split2(val, h, l);
        Tkh[t2] = h; Tkl[t2] = l;
    }
    int t3 = g - 20480;
    if (t3 >= 0 && t3 < 16384) {
        int row = t3 >> 8, h = t3 & 255;
        int ky = row & 31;
        int phys = (ky < 16) ? ky : (224 + ky);
        int ph = (phys * h) & 255;
        float s, c; sincosf((float)ph * TWO_PI_256, &s, &c);
        float val = (row < 32) ? c : s;
        ushort hh, ll; split2(val, hh, ll);
        Th2h[t3] = hh; Th2l[t3] = ll;
    }
    int t4 = g - 36864;
    if (t4 >= 0 && t4 < 16384) {
        int h = t4 >> 6, col = t4 & 63;
        int ky = col & 31;
        int phys = (ky < 16) ? ky : (224 + ky);
        int ph = (phys * h) & 255;
        float s, c; sincosf((float)ph * TWO_PI_256, &s, &c);
        float val = (col < 32) ? c : s;
        ushort hh, ll; split2(val, hh, ll);
        Th4h[t4] = hh; Th4l[t4] = ll;
    }
}

// ---------------- Pass 1+2 fused: w-DFT then h-DFT, one block per plane ----------------
// x staged bf16-HI only (2-product w-DFT: x_hi*(Tk_hi+Tk_lo)); Xw intermediate
// keeps full hi/lo split for the h-DFT (3 products there).
__global__ __launch_bounds__(256) void k_spec(const float* __restrict__ x,
        const ushort* __restrict__ Tkh, const ushort* __restrict__ Tkl,
        const ushort* __restrict__ Th2h, const ushort* __restrict__ Th2l,
        float2* __restrict__ XhT) {
    const int tid = threadIdx.x;
    const int lane = tid & 63;
    const int wv = tid >> 6;
    const int bid = blockIdx.x;
    const int bc = ((bid & 7) << 7) + (bid >> 3);     // XCD-chunked (bijective, 1024 = 8*128)
    const int l15 = lane & 15, l4 = lane >> 4;
    const int mt = wv >> 1, nt = wv & 1;

    __shared__ ushort Ah[32 * 256];    // chunk x bf16-hi, octet^(h&7) swizzled
    __shared__ ushort Xwh[32 * 256];   // [col][h] bf16-hi, h-octet^(col&7) swizzled
    __shared__ ushort Xwl[32 * 256];
    __shared__ float  Dl[64 * 33];

    const float* xp = x + ((size_t)bc << 16);

    const int rbase = ((mt << 4) + l15) << 8;          // A row base (ushorts)
    const int rs = ((mt << 4) + l15) & 7;
    const int jrow = (nt << 4) + l15;                  // Tk row / Xw col

#define LDCH(pf, c) { \
    _Pragma("unroll") \
    for (int i_ = 0; i_ < 4; ++i_) { \
        int f8_ = tid + (i_ << 8); \
        int hh_ = f8_ >> 5, oct_ = f8_ & 31; \
        const float* p_ = xp + (((c) << 5) + hh_) * 256 + (oct_ << 3); \
        *(float4*)&pf[i_ * 8]     = *(const float4*)(p_); \
        *(float4*)&pf[i_ * 8 + 4] = *(const float4*)(p_ + 4); \
    } }

#define STAGE_A(pf) { \
    _Pragma("unroll") \
    for (int i_ = 0; i_ < 4; ++i_) { \
        int f8_ = tid + (i_ << 8); \
        int hh_ = f8_ >> 5, oct_ = f8_ & 31; \
        bf16x8 hi8_; \
        cvt8_hi(&pf[i_ * 8], hi8_); \
        int bx_ = oct_ ^ (hh_ & 7); \
        *(bf16x8*)(&Ah[(hh_ << 8) + (bx_ << 3)]) = hi8_; \
    } }

    float pfA[32], pfB[32];
    LDCH(pfA, 0);
    LDCH(pfB, 1);

    #pragma unroll
    for (int c = 0; c < 8; ++c) {
        __syncthreads();                 // prior chunk's A reads complete
        if (c & 1) { STAGE_A(pfB); } else { STAGE_A(pfA); }
        __syncthreads();
        if (c + 2 < 8) {                 // refill the just-consumed buffer
            if (c & 1) { LDCH(pfB, c + 2); } else { LDCH(pfA, c + 2); }
        }

        f32x4 acc = {0.f, 0.f, 0.f, 0.f};
        #pragma unroll
        for (int ks = 0; ks < 8; ++ks) {
            int boff = ((((ks << 2) + l4) ^ rs) << 3);
            bf16x8 a_h = *(const bf16x8*)(&Ah[rbase + boff]);
            int toff = (jrow << 8) + (ks << 5) + (l4 << 3);
            bf16x8 b_h = *(const bf16x8*)(Tkh + toff);
            bf16x8 b_l = *(const bf16x8*)(Tkl + toff);
            acc = __builtin_amdgcn_mfma_f32_16x16x32_bf16(a_h, b_h, acc, 0, 0, 0);
            acc = __builtin_amdgcn_mfma_f32_16x16x32_bf16(a_h, b_l, acc, 0, 0, 0);
        }
        // D: col=jrow, h = c*32 + mt*16 + l4*4 + r. nt=1 rows are sin -> Im = -acc.
        ushort hi4[4], lo4[4];
        #pragma unroll
        for (int r = 0; r < 4; ++r) {
            float v = nt ? -acc[r] : acc[r];
            split2(v, hi4[r], lo4[r]);
        }
        int habs = (c << 5) + (mt << 4) + (l4 << 2);
        int op = (habs >> 3) ^ (jrow & 7);
        int addr = (jrow << 8) + (op << 3) + (habs & 7);
        *(ushort4*)(&Xwh[addr]) = *(ushort4*)hi4;
        *(ushort4*)(&Xwl[addr]) = *(ushort4*)lo4;
    }
    __syncthreads();                     // Xw writes visible

    // ---- h-DFT: D2[64 ky'][32 col] = Th2 * Xw ----
    f32x4 acc2[2];
    acc2[0] = (f32x4){0.f, 0.f, 0.f, 0.f};
    acc2[1] = (f32x4){0.f, 0.f, 0.f, 0.f};
    const int arow = (wv << 4) + l15;
    #pragma unroll
    for (int ks = 0; ks < 8; ++ks) {
        int aoff = (arow << 8) + (ks << 5) + (l4 << 3);
        bf16x8 a_h = *(const bf16x8*)(Th2h + aoff);
        bf16x8 a_l = *(const bf16x8*)(Th2l + aoff);
        #pragma unroll
        for (int nt2 = 0; nt2 < 2; ++nt2) {
            int col = (nt2 << 4) + l15;
            int oi = ((ks << 2) + l4) ^ (col & 7);
            bf16x8 b_h = *(const bf16x8*)(&Xwh[(col << 8) + (oi << 3)]);
            bf16x8 b_l = *(const bf16x8*)(&Xwl[(col << 8) + (oi << 3)]);
            acc2[nt2] = __builtin_amdgcn_mfma_f32_16x16x32_bf16(a_h, b_h, acc2[nt2], 0, 0, 0);
            acc2[nt2] = __builtin_amdgcn_mfma_f32_16x16x32_bf16(a_h, b_l, acc2[nt2], 0, 0, 0);
            acc2[nt2] = __builtin_amdgcn_mfma_f32_16x16x32_bf16(a_l, b_h, acc2[nt2], 0, 0, 0);
        }
    }
    #pragma unroll
    for (int nt2 = 0; nt2 < 2; ++nt2)
        #pragma unroll
        for (int r = 0; r < 4; ++r)
            Dl[((wv << 4) + (l4 << 2) + r) * 33 + (nt2 << 4) + l15] = acc2[nt2][r];
    __syncthreads();

    #pragma unroll
    for (int q = 0; q < 2; ++q) {
        int m = tid + (q << 8);
        int ky = m >> 4, kx = m & 15;
        float re = Dl[ky * 33 + kx] + Dl[(32 + ky) * 33 + 16 + kx];
        float im = Dl[ky * 33 + 16 + kx] - Dl[(32 + ky) * 33 + kx];
        XhT[((size_t)m << 10) + bc] = make_float2(re, im);
    }
#undef LDCH
#undef STAGE_A
}

// ---------------- Pass 3: channel mix, coalesced-weight version ----------------
__global__ __launch_bounds__(256) void k_modes(const float2* __restrict__ XhT,
        const float* __restrict__ w1r, const float* __restrict__ w1i,
        const float* __restrict__ w2r, const float* __restrict__ w2i,
        float2* __restrict__ S) {
    const int tid = threadIdx.x;
    const int kyIdx = blockIdx.x >> 3;
    const int oc    = blockIdx.x & 7;
    const int xy0   = (kyIdx & 15) << 4;
    const float* __restrict__ wr = (kyIdx < 16) ? w1r : w2r;
    const float* __restrict__ wi = (kyIdx < 16) ? w1i : w2i;

    __shared__ float2 Xl[16][16][17];
    __shared__ float  Wr_l[16][8][20];
    __shared__ float  Wi_l[16][8][20];

    const int b  = tid >> 4;
    const int o8 = (tid >> 1) & 7;
    const int kh = tid & 1;

    const int s_ii = tid >> 4, s_oj = (tid >> 1) & 7, s_part = tid & 1;
    const int s_kx = tid >> 4, s_bb = tid & 15;

    float2 acc[8];
    #pragma unroll
    for (int j = 0; j < 8; ++j) acc[j] = make_float2(0.f, 0.f);

    for (int ic = 0; ic < 4; ++ic) {
        if (ic) __syncthreads();
        {
            const float* src = s_part ? wi : wr;
            size_t off = ((size_t)(((ic << 4) + s_ii) * 64 + (oc << 3) + s_oj) << 8) + xy0;
            float4 v0 = *(const float4*)(src + off);
            float4 v1 = *(const float4*)(src + off + 4);
            float4 v2 = *(const float4*)(src + off + 8);
            float4 v3 = *(const float4*)(src + off + 12);
            float* dst = s_part ? &Wi_l[s_ii][s_oj][0] : &Wr_l[s_ii][s_oj][0];
            *(float4*)(dst)      = v0;
            *(float4*)(dst + 4)  = v1;
            *(float4*)(dst + 8)  = v2;
            *(float4*)(dst + 12) = v3;
        }
        {
            const float2* src = XhT + (((size_t)((kyIdx << 4) + s_kx)) << 10)
                                    + (s_bb << 6) + (ic << 4);
            float2 xv[16];
            #pragma unroll
            for (int q = 0; q < 8; ++q)
                *(float4*)&xv[q << 1] = *(const float4*)(src + (q << 1));
            #pragma unroll
            for (int ii = 0; ii < 16; ++ii)
                Xl[s_kx][ii][s_bb] = xv[ii];
        }
        __syncthreads();

        #pragma unroll 4
        for (int ii = 0; ii < 16; ++ii) {
            float4 wr0 = *(const float4*)&Wr_l[ii][o8][kh << 3];
            float4 wr1 = *(const float4*)&Wr_l[ii][o8][(kh << 3) + 4];
            float4 wi0 = *(const float4*)&Wi_l[ii][o8][kh << 3];
            float4 wi1 = *(const float4*)&Wi_l[ii][o8][(kh << 3) + 4];
            const float wrv[8] = {wr0.x, wr0.y, wr0.z, wr0.w, wr1.x, wr1.y, wr1.z, wr1.w};
            const float wiv[8] = {wi0.x, wi0.y, wi0.z, wi0.w, wi1.x, wi1.y, wi1.z, wi1.w};
            #pragma unroll
            for (int j = 0; j < 8; ++j) {
                float2 xv = Xl[(kh << 3) + j][ii][b];
                acc[j].x = fmaf(xv.x, wrv[j], fmaf(-xv.y, wiv[j], acc[j].x));
                acc[j].y = fmaf(xv.x, wiv[j], fmaf( xv.y, wrv[j], acc[j].y));
            }
        }
    }

    const float sc = 1.52587890625e-05f;   // 1/65536
    const int o = (oc << 3) + o8;
    float2* sp = S + (((size_t)(b << 6) + o) << 9) + (kyIdx << 4) + (kh << 3);
    #pragma unroll
    for (int q = 0; q < 4; ++q) {
        float4 v = make_float4(acc[2 * q].x * sc, acc[2 * q].y * sc,
                               acc[2 * q + 1].x * sc, acc[2 * q + 1].y * sc);
        *(float4*)(sp + (q << 1)) = v;
    }
}

// ---------------- Pass 4: inverse DFT over h via MFMA ----------------
static __device__ __forceinline__ void sb_put(ushort* Sbh, ushort* Sbl,
                                              int rr, int cc, float vv) {
    ushort hh, ll; split2(vv, hh, ll);
    int idx = (cc << 6) + ((((rr) >> 3) ^ (cc & 7)) << 3) + (rr & 7);
    Sbh[idx] = hh; Sbl[idx] = ll;
}

__global__ __launch_bounds__(256) void k_invh(const float2* __restrict__ S,
        const ushort* __restrict__ Th4h, const ushort* __restrict__ Th4l,
        ushort* __restrict__ Abh, ushort* __restrict__ Abl) {
    const int tid = threadIdx.x;
    const int lane = tid & 63;
    const int wv = tid >> 6;
    const int bid = blockIdx.x;
    const int bo = ((bid & 7) << 7) + (bid >> 3);     // XCD-chunked
    const int b = bo >> 6, o = bo & 63;
    const int l15 = lane & 15, l4 = lane >> 4;

    __shared__ ushort Sbh[2048];
    __shared__ ushort Sbl[2048];
    __shared__ float  Dl[256 * 33];

    {
        float4 sv = *(const float4*)(S + ((size_t)bo << 9) + (tid << 1));
        #pragma unroll
        for (int j = 0; j < 2; ++j) {
            int m = (tid << 1) + j;
            int ky = m >> 4, kx = m & 15;
            float sr = j ? sv.z : sv.x;
            float si = j ? sv.w : sv.y;
            float scl = kx ? 2.0f : 1.0f;
            sr *= scl; si *= scl;
            sb_put(Sbh, Sbl, ky,      kx,      sr);
            sb_put(Sbh, Sbl, 32 + ky, kx,     -si);
            sb_put(Sbh, Sbl, ky,      16 + kx, -si);
            sb_put(Sbh, Sbl, 32 + ky, 16 + kx, -sr);
        }
    }
    __syncthreads();

    f32x4 acc[4][2];
    #pragma unroll
    for (int i = 0; i < 4; ++i)
        #pragma unroll
        for (int nt = 0; nt < 2; ++nt)
            acc[i][nt] = (f32x4){0.f, 0.f, 0.f, 0.f};

    #pragma unroll
    for (int i = 0; i < 4; ++i) {
        const int hrow = (((wv << 2) + i) << 4) + l15;
        #pragma unroll
        for (int ks = 0; ks < 2; ++ks) {
            int aoff = (hrow << 6) + (ks << 5) + (l4 << 3);
            bf16x8 a_h = *(const bf16x8*)(Th4h + aoff);
            bf16x8 a_l = *(const bf16x8*)(Th4l + aoff);
            #pragma unroll
            for (int nt = 0; nt < 2; ++nt) {
                int col = (nt << 4) + l15;
                int oi = ((ks << 2) + l4) ^ (col & 7);
                bf16x8 b_h = *(const bf16x8*)(&Sbh[(col << 6) + (oi << 3)]);
                bf16x8 b_l = *(const bf16x8*)(&Sbl[(col << 6) + (oi << 3)]);
                acc[i][nt] = __builtin_amdgcn_mfma_f32_16x16x32_bf16(a_h, b_h, acc[i][nt], 0, 0, 0);
                acc[i][nt] = __builtin_amdgcn_mfma_f32_16x16x32_bf16(a_h, b_l, acc[i][nt], 0, 0, 0);
                acc[i][nt] = __builtin_amdgcn_mfma_f32_16x16x32_bf16(a_l, b_h, acc[i][nt], 0, 0, 0);
            }
        }
    }
    #pragma unroll
    for (int i = 0; i < 4; ++i)
        #pragma unroll
        for (int nt = 0; nt < 2; ++nt)
            #pragma unroll
            for (int r = 0; r < 4; ++r)
                Dl[((((wv << 2) + i) << 4) + (l4 << 2) + r) * 33 + (nt << 4) + l15]
                    = acc[i][nt][r];
    __syncthreads();

    {
        const int h = tid;
        ushort hi[32], lo[32];
        #pragma unroll
        for (int j = 0; j < 32; ++j)
            split2(Dl[h * 33 + j], hi[j], lo[j]);
        size_t base = (((size_t)((b << 8) + h)) << 11) + (o << 5);
        *(uint4*)(Abh + base)      = *(uint4*)&hi[0];
        *(uint4*)(Abh + base + 8)  = *(uint4*)&hi[8];
        *(uint4*)(Abh + base + 16) = *(uint4*)&hi[16];
        *(uint4*)(Abh + base + 24) = *(uint4*)&hi[24];
        *(uint4*)(Abl + base)      = *(uint4*)&lo[0];
        *(uint4*)(Abl + base + 8)  = *(uint4*)&lo[8];
        *(uint4*)(Abl + base + 16) = *(uint4*)&lo[16];
        *(uint4*)(Abl + base + 24) = *(uint4*)&lo[24];
    }
}

// ---------------- Pass 5: MFMA conv + inv-DFT-w + bias + GELU ----------------
// r7 schedule; B-operand ([x | Tg]) bf16-HI only -> 2-product MFMA
// (A=[Wc|Z] keeps hi/lo), single Xh LDS buffer (16 KB), cvt-hi staging.
__global__ __launch_bounds__(256, 3) void k_final(const float* __restrict__ x,
        const ushort* __restrict__ Wch, const ushort* __restrict__ Wcl,
        const ushort* __restrict__ Tgh, const ushort* __restrict__ Tgl,
        const ushort* __restrict__ Abh, const ushort* __restrict__ Abl,
        const float* __restrict__ bcv, float* __restrict__ out) {
    const int tid = threadIdx.x;
    const int lane = tid & 63;
    const int wv = tid >> 6;
    const int bid = blockIdx.x;
    const int gid = ((bid >> 5) << 3) | (bid & 7);
    const int wq  = (bid >> 3) & 3;
    const int b = gid >> 6, ht = gid & 63;
    const int w0 = wq << 6;

    __shared__ ushort Xh[64][128];

    const int l15 = lane & 15, l4 = lane >> 4;
    const int mt0 = (wv >> 1) << 1;
    const int nt0 = (wv & 1) << 1;
    const int wloc = tid & 63, cb0 = tid >> 6;

    const float* xb = x + ((size_t)b << 22) + ((size_t)(ht << 2) << 8) + w0 + wloc;

    float g[2][2][8];
    #pragma unroll
    for (int i = 0; i < 2; ++i) {
        const float* xpc = xb + ((size_t)(cb0 + (i << 2)) << 19);
        #pragma unroll
        for (int j = 0; j < 8; ++j) g[0][i][j] = xpc[(size_t)j << 16];
    }

    {
        size_t gg = ((size_t)(w0 + wloc) << 5) + (cb0 << 3);
        bf16x8 th = *(const bf16x8*)(Tgh + gg);
        int bidx = (8 + cb0) ^ (wloc & 7);
        *(bf16x8*)(&Xh[0][0] + (wloc << 7) + (bidx << 3)) = th;
    }

    bf16x8 aW[2][2][2];
    #pragma unroll
    for (int mi = 0; mi < 2; ++mi) {
        int o = ((mt0 + mi) << 4) + l15;
        #pragma unroll
        for (int ks = 0; ks < 2; ++ks) {
            size_t gg = ((size_t)o << 6) + (ks << 5) + (l4 << 3);
            aW[mi][ks][0] = *(const bf16x8*)(Wch + gg);
            aW[mi][ks][1] = *(const bf16x8*)(Wcl + gg);
        }
    }
    float bias[2][4];
    #pragma unroll
    for (int mi = 0; mi < 2; ++mi)
        #pragma unroll
        for (int r = 0; r < 4; ++r)
            bias[mi][r] = bcv[((mt0 + mi) << 4) + (l4 << 2) + r];

    #pragma unroll
    for (int hh = 0; hh < 4; ++hh) {
        const int h = (ht << 2) + hh;
        const int cur = hh & 1, nxt = cur ^ 1;

        bf16x8 zH[2], zL[2];
        #pragma unroll
        for (int mi = 0; mi < 2; ++mi) {
            int o = ((mt0 + mi) << 4) + l15;
            size_t gg = ((((size_t)((b << 8) + h) << 6) + o) << 5) + (l4 << 3);
            zH[mi] = *(const bf16x8*)(Abh + gg);
            zL[mi] = *(const bf16x8*)(Abl + gg);
        }

        bf16x8 hb[2];
        cvt8_hi(g[cur][0], hb[0]);
        cvt8_hi(g[cur][1], hb[1]);

        __syncthreads();
        #pragma unroll
        for (int i = 0; i < 2; ++i) {
            int bidx = (cb0 + (i << 2)) ^ (wloc & 7);
            *(bf16x8*)(&Xh[0][0] + (wloc << 7) + (bidx << 3)) = hb[i];
        }
        __syncthreads();

        // prefetch next h's x here: loads stay in flight through MFMA+epilogue
        // and the next iteration's Z-loads; drained at the NEXT barrier.
        if (hh < 3) {
            #pragma unroll
            for (int i = 0; i < 2; ++i) {
                const float* xpc = xb + ((size_t)(cb0 + (i << 2)) << 19) + ((hh + 1) << 8);
                #pragma unroll
                for (int j = 0; j < 8; ++j) g[nxt][i][j] = xpc[(size_t)j << 16];
            }
        }

        f32x4 acc[2][2];
        #pragma unroll
        for (int mi = 0; mi < 2; ++mi)
            #pragma unroll
            for (int ni = 0; ni < 2; ++ni)
                acc[mi][ni] = (f32x4){0.f, 0.f, 0.f, 0.f};

        #pragma unroll
        for (int ks = 0; ks < 3; ++ks) {
            bf16x8 bh[2];
            #pragma unroll
            for (int ni = 0; ni < 2; ++ni) {
                int w = ((nt0 + ni) << 4) + l15;
                int bidx = ((ks << 2) + l4) ^ (w & 7);
                bh[ni] = *(const bf16x8*)(&Xh[0][0] + (w << 7) + (bidx << 3));
            }
            #pragma unroll
            for (int mi = 0; mi < 2; ++mi) {
                bf16x8 ah_ = (ks < 2) ? aW[mi][ks][0] : zH[mi];
                bf16x8 al_ = (ks < 2) ? aW[mi][ks][1] : zL[mi];
                #pragma unroll
                for (int ni = 0; ni < 2; ++ni) {
                    acc[mi][ni] = __builtin_amdgcn_mfma_f32_16x16x32_bf16(ah_, bh[ni], acc[mi][ni], 0, 0, 0);
                    acc[mi][ni] = __builtin_amdgcn_mfma_f32_16x16x32_bf16(al_, bh[ni], acc[mi][ni], 0, 0, 0);
                }
            }
        }

        #pragma unroll
        for (int mi = 0; mi < 2; ++mi) {
            #pragma unroll
            for (int ni = 0; ni < 2; ++ni) {
                int wg = w0 + ((nt0 + ni) << 4) + l15;
                #pragma unroll
                for (int r = 0; r < 4; ++r) {
                    int o = ((mt0 + mi) << 4) + (l4 << 2) + r;
                    float v = acc[mi][ni][r] + bias[mi][r];
                    out[((size_t)((b << 6) + o) << 16) + ((size_t)h << 8) + wg] = gelu_f(v);
                }
            }
        }
    }
}

extern "C" void kernel_launch(void* const* d_in, const int* in_sizes, int n_in,
                              void* d_out, int out_size, void* d_ws, size_t ws_size,
                              hipStream_t stream) {
    const float* x   = (const float*)d_in[0];
    const float* Wc  = (const float*)d_in[1];
    const float* bcv = (const float*)d_in[2];
    const float* w1r = (const float*)d_in[3];
    const float* w1i = (const float*)d_in[4];
    const float* w2r = (const float*)d_in[5];
    const float* w2i = (const float*)d_in[6];
    float* out = (float*)d_out;

    // Workspace (42.2 MB):
    //   [0, 33.5M):  Abh|Abl (pass4->5)
    //   [33.5M):     XhT 4M    [37.7M): S 4M    [41.9M+): tables
    char* wsb = (char*)d_ws;
    ushort* Abh  = (ushort*)wsb;
    ushort* Abl  = (ushort*)(wsb + 16777216);
    float2* XhT  = (float2*)(wsb + 33554432);
    float2* S    = (float2*)(wsb + 37748736);
    ushort* Wch  = (ushort*)(wsb + 41943040);
    ushort* Wcl  = (ushort*)(wsb + 41951232);
    ushort* Tgh  = (ushort*)(wsb + 41959424);
    ushort* Tgl  = (ushort*)(wsb + 41975808);
    ushort* Tkh  = (ushort*)(wsb + 41992192);
    ushort* Tkl  = (ushort*)(wsb + 42008576);
    ushort* Th2h = (ushort*)(wsb + 42024960);
    ushort* Th2l = (ushort*)(wsb + 42057728);
    ushort* Th4h = (ushort*)(wsb + 42090496);
    ushort* Th4l = (ushort*)(wsb + 42123264);

    k_prep <<< 208, 256, 0, stream>>>(Wc, Wch, Wcl, Tgh, Tgl, Tkh, Tkl,
                                      Th2h, Th2l, Th4h, Th4l);
    k_spec <<<1024, 256, 0, stream>>>(x, Tkh, Tkl, Th2h, Th2l, XhT);
    k_modes<<< 256, 256, 0, stream>>>(XhT, w1r, w1i, w2r, w2i, S);
    k_invh <<<1024, 256, 0, stream>>>(S, Th4h, Th4l, Abh, Abl);
    k_final<<<4096, 256, 0, stream>>>(x, Wch, Wcl, Tgh, Tgl, Abh, Abl, bcv, out);
}

// Round 11
// 257.291 us; speedup vs baseline: 1.8132x; 1.0561x over previous
//
#include <hip/hip_runtime.h>
#include <hip/hip_bf16.h>
#include <math.h>

#define TWO_PI_256 0.024543692606170259678f  // 2*pi/256

typedef __attribute__((ext_vector_type(8))) short bf16x8;
typedef __attribute__((ext_vector_type(4))) float f32x4;

static __device__ __forceinline__ ushort bf16_rn(float a) {
    union { float f; unsigned int u; } v; v.f = a;
    unsigned int r = v.u + 0x7FFFu + ((v.u >> 16) & 1u);
    return (ushort)(r >> 16);
}
static __device__ __forceinline__ float bf16_to_f(ushort h) {
    union { unsigned int u; float f; } v; v.u = ((unsigned int)h) << 16;
    return v.f;
}
static __device__ __forceinline__ void split2(float a, ushort& hi, ushort& lo) {
    ushort h = bf16_rn(a);
    hi = h;
    lo = bf16_rn(a - bf16_to_f(h));
}

// hi-only: 8 floats -> bf16 x8 (4 cvt_pk)
static __device__ __forceinline__ void cvt8_hi(const float* v, bf16x8& hi8) {
    union { ushort u[8]; bf16x8 v8; } H;
    #pragma unroll
    for (int j = 0; j < 8; j += 2) {
        __hip_bfloat162 hb = __float22bfloat162_rn(make_float2(v[j], v[j + 1]));
        ushort2 hu = *reinterpret_cast<ushort2*>(&hb);
        H.u[j] = hu.x; H.u[j + 1] = hu.y;
    }
    hi8 = H.v8;
}

// branchless tanh-form GELU (max |delta| vs exact-erf gelu ~5e-4)
static __device__ __forceinline__ float gelu_f(float v) {
    float z = v * fmaf(v * v, 0.10294321f, 2.3022082f);   // 2u/ln2
    float e = __builtin_amdgcn_exp2f(z);
    return v - v * __builtin_amdgcn_rcpf(e + 1.0f);
}

// ---------------- Pass 0: bf16-split tables ----------------
__global__ __launch_bounds__(256) void k_prep(const float* __restrict__ Wc,
        ushort* __restrict__ Wch, ushort* __restrict__ Wcl,
        ushort* __restrict__ Tgh, ushort* __restrict__ Tgl,
        ushort* __restrict__ Tkh, ushort* __restrict__ Tkl,
        ushort* __restrict__ Th2h, ushort* __restrict__ Th2l,
        ushort* __restrict__ Th4h, ushort* __restrict__ Th4l) {
    int g = blockIdx.x * 256 + threadIdx.x;
    if (g < 4096) {
        ushort h, l; split2(Wc[g], h, l);
        Wch[g] = h; Wcl[g] = l;
    }
    int t = g - 4096;
    if (t >= 0 && t < 8192) {
        int w = t >> 5, kz = t & 31, kx = kz & 15;
        int ph = (w * kx) & 255;
        float s, c; sincosf((float)ph * TWO_PI_256, &s, &c);
        float val = (kz < 16) ? c : s;
        ushort h, l; split2(val, h, l);
        Tgh[t] = h; Tgl[t] = l;
    }
    int t2 = g - 12288;
    if (t2 >= 0 && t2 < 8192) {
        int j = t2 >> 8, w = t2 & 255, kx = j & 15;
        int ph = (w * kx) & 255;
        float s, c; sincosf((float)ph * TWO_PI_256, &s, &c);
        float val = (j < 16) ? c : s;
        ushort h, l; split2(val, h, l);
        Tkh[t2] = h; Tkl[t2] = l;
    }
    int t3 = g - 20480;
    if (t3 >= 0 && t3 < 16384) {
        int row = t3 >> 8, h = t3 & 255;
        int ky = row & 31;
        int phys = (ky < 16) ? ky : (224 + ky);
        int ph = (phys * h) & 255;
        float s, c; sincosf((float)ph * TWO_PI_256, &s, &c);
        float val = (row < 32) ? c : s;
        ushort hh, ll; split2(val, hh, ll);
        Th2h[t3] = hh; Th2l[t3] = ll;
    }
    int t4 = g - 36864;
    if (t4 >= 0 && t4 < 16384) {
        int h = t4 >> 6, col = t4 & 63;
        int ky = col & 31;
        int phys = (ky < 16) ? ky : (224 + ky);
        int ph = (phys * h) & 255;
        float s, c; sincosf((float)ph * TWO_PI_256, &s, &c);
        float val = (col < 32) ? c : s;
        ushort hh, ll; split2(val, hh, ll);
        Th4h[t4] = hh; Th4l[t4] = ll;
    }
}

// ---------------- Pass 1+2 fused: w-DFT then h-DFT, one block per plane ----------------
// x staged bf16-HI only; Xw intermediate ALSO hi-only (h-DFT: (Th2h+Th2l)*Xw_hi).
// LDS 40.6 KB -> 3 blocks/CU (12 waves) — k_spec is latency-bound, occupancy is the lever.
__global__ __launch_bounds__(256, 3) void k_spec(const float* __restrict__ x,
        const ushort* __restrict__ Tkh, const ushort* __restrict__ Tkl,
        const ushort* __restrict__ Th2h, const ushort* __restrict__ Th2l,
        float2* __restrict__ XhT) {
    const int tid = threadIdx.x;
    const int lane = tid & 63;
    const int wv = tid >> 6;
    const int bid = blockIdx.x;
    const int bc = ((bid & 7) << 7) + (bid >> 3);     // XCD-chunked (bijective, 1024 = 8*128)
    const int l15 = lane & 15, l4 = lane >> 4;
    const int mt = wv >> 1, nt = wv & 1;

    __shared__ ushort Ah[32 * 256];    // chunk x bf16-hi, octet^(h&7) swizzled
    __shared__ ushort Xwh[32 * 256];   // [col][h] bf16-hi, h-octet^(col&7) swizzled
    __shared__ float  Dl[64 * 33];

    const float* xp = x + ((size_t)bc << 16);

    const int rbase = ((mt << 4) + l15) << 8;          // A row base (ushorts)
    const int rs = ((mt << 4) + l15) & 7;
    const int jrow = (nt << 4) + l15;                  // Tk row / Xw col

#define LDCH(pf, c) { \
    _Pragma("unroll") \
    for (int i_ = 0; i_ < 4; ++i_) { \
        int f8_ = tid + (i_ << 8); \
        int hh_ = f8_ >> 5, oct_ = f8_ & 31; \
        const float* p_ = xp + (((c) << 5) + hh_) * 256 + (oct_ << 3); \
        *(float4*)&pf[i_ * 8]     = *(const float4*)(p_); \
        *(float4*)&pf[i_ * 8 + 4] = *(const float4*)(p_ + 4); \
    } }

#define STAGE_A(pf) { \
    _Pragma("unroll") \
    for (int i_ = 0; i_ < 4; ++i_) { \
        int f8_ = tid + (i_ << 8); \
        int hh_ = f8_ >> 5, oct_ = f8_ & 31; \
        bf16x8 hi8_; \
        cvt8_hi(&pf[i_ * 8], hi8_); \
        int bx_ = oct_ ^ (hh_ & 7); \
        *(bf16x8*)(&Ah[(hh_ << 8) + (bx_ << 3)]) = hi8_; \
    } }

    float pfA[32], pfB[32];
    LDCH(pfA, 0);
    LDCH(pfB, 1);

    #pragma unroll
    for (int c = 0; c < 8; ++c) {
        __syncthreads();                 // prior chunk's A reads complete
        if (c & 1) { STAGE_A(pfB); } else { STAGE_A(pfA); }
        __syncthreads();
        if (c + 2 < 8) {                 // refill the just-consumed buffer
            if (c & 1) { LDCH(pfB, c + 2); } else { LDCH(pfA, c + 2); }
        }

        f32x4 acc = {0.f, 0.f, 0.f, 0.f};
        #pragma unroll
        for (int ks = 0; ks < 8; ++ks) {
            int boff = ((((ks << 2) + l4) ^ rs) << 3);
            bf16x8 a_h = *(const bf16x8*)(&Ah[rbase + boff]);
            int toff = (jrow << 8) + (ks << 5) + (l4 << 3);
            bf16x8 b_h = *(const bf16x8*)(Tkh + toff);
            bf16x8 b_l = *(const bf16x8*)(Tkl + toff);
            acc = __builtin_amdgcn_mfma_f32_16x16x32_bf16(a_h, b_h, acc, 0, 0, 0);
            acc = __builtin_amdgcn_mfma_f32_16x16x32_bf16(a_h, b_l, acc, 0, 0, 0);
        }
        // D: col=jrow, h = c*32 + mt*16 + l4*4 + r. nt=1 rows are sin -> Im = -acc.
        ushort hi4[4];
        #pragma unroll
        for (int r = 0; r < 4; ++r) {
            float v = nt ? -acc[r] : acc[r];
            hi4[r] = bf16_rn(v);
        }
        int habs = (c << 5) + (mt << 4) + (l4 << 2);
        int op = (habs >> 3) ^ (jrow & 7);
        int addr = (jrow << 8) + (op << 3) + (habs & 7);
        *(ushort4*)(&Xwh[addr]) = *(ushort4*)hi4;
    }
    __syncthreads();                     // Xw writes visible

    // ---- h-DFT: D2[64 ky'][32 col] = (Th2h+Th2l) * Xw_hi ----
    f32x4 acc2[2];
    acc2[0] = (f32x4){0.f, 0.f, 0.f, 0.f};
    acc2[1] = (f32x4){0.f, 0.f, 0.f, 0.f};
    const int arow = (wv << 4) + l15;
    #pragma unroll
    for (int ks = 0; ks < 8; ++ks) {
        int aoff = (arow << 8) + (ks << 5) + (l4 << 3);
        bf16x8 a_h = *(const bf16x8*)(Th2h + aoff);
        bf16x8 a_l = *(const bf16x8*)(Th2l + aoff);
        #pragma unroll
        for (int nt2 = 0; nt2 < 2; ++nt2) {
            int col = (nt2 << 4) + l15;
            int oi = ((ks << 2) + l4) ^ (col & 7);
            bf16x8 b_h = *(const bf16x8*)(&Xwh[(col << 8) + (oi << 3)]);
            acc2[nt2] = __builtin_amdgcn_mfma_f32_16x16x32_bf16(a_h, b_h, acc2[nt2], 0, 0, 0);
            acc2[nt2] = __builtin_amdgcn_mfma_f32_16x16x32_bf16(a_l, b_h, acc2[nt2], 0, 0, 0);
        }
    }
    #pragma unroll
    for (int nt2 = 0; nt2 < 2; ++nt2)
        #pragma unroll
        for (int r = 0; r < 4; ++r)
            Dl[((wv << 4) + (l4 << 2) + r) * 33 + (nt2 << 4) + l15] = acc2[nt2][r];
    __syncthreads();

    #pragma unroll
    for (int q = 0; q < 2; ++q) {
        int m = tid + (q << 8);
        int ky = m >> 4, kx = m & 15;
        float re = Dl[ky * 33 + kx] + Dl[(32 + ky) * 33 + 16 + kx];
        float im = Dl[ky * 33 + 16 + kx] - Dl[(32 + ky) * 33 + kx];
        XhT[((size_t)m << 10) + bc] = make_float2(re, im);
    }
#undef LDCH
#undef STAGE_A
}

// ---------------- Pass 3: channel mix, coalesced-weight version ----------------
__global__ __launch_bounds__(256) void k_modes(const float2* __restrict__ XhT,
        const float* __restrict__ w1r, const float* __restrict__ w1i,
        const float* __restrict__ w2r, const float* __restrict__ w2i,
        float2* __restrict__ S) {
    const int tid = threadIdx.x;
    const int kyIdx = blockIdx.x >> 3;
    const int oc    = blockIdx.x & 7;
    const int xy0   = (kyIdx & 15) << 4;
    const float* __restrict__ wr = (kyIdx < 16) ? w1r : w2r;
    const float* __restrict__ wi = (kyIdx < 16) ? w1i : w2i;

    __shared__ float2 Xl[16][16][17];
    __shared__ float  Wr_l[16][8][20];
    __shared__ float  Wi_l[16][8][20];

    const int b  = tid >> 4;
    const int o8 = (tid >> 1) & 7;
    const int kh = tid & 1;

    const int s_ii = tid >> 4, s_oj = (tid >> 1) & 7, s_part = tid & 1;
    const int s_kx = tid >> 4, s_bb = tid & 15;

    float2 acc[8];
    #pragma unroll
    for (int j = 0; j < 8; ++j) acc[j] = make_float2(0.f, 0.f);

    for (int ic = 0; ic < 4; ++ic) {
        if (ic) __syncthreads();
        {
            const float* src = s_part ? wi : wr;
            size_t off = ((size_t)(((ic << 4) + s_ii) * 64 + (oc << 3) + s_oj) << 8) + xy0;
            float4 v0 = *(const float4*)(src + off);
            float4 v1 = *(const float4*)(src + off + 4);
            float4 v2 = *(const float4*)(src + off + 8);
            float4 v3 = *(const float4*)(src + off + 12);
            float* dst = s_part ? &Wi_l[s_ii][s_oj][0] : &Wr_l[s_ii][s_oj][0];
            *(float4*)(dst)      = v0;
            *(float4*)(dst + 4)  = v1;
            *(float4*)(dst + 8)  = v2;
            *(float4*)(dst + 12) = v3;
        }
        {
            const float2* src = XhT + (((size_t)((kyIdx << 4) + s_kx)) << 10)
                                    + (s_bb << 6) + (ic << 4);
            float2 xv[16];
            #pragma unroll
            for (int q = 0; q < 8; ++q)
                *(float4*)&xv[q << 1] = *(const float4*)(src + (q << 1));
            #pragma unroll
            for (int ii = 0; ii < 16; ++ii)
                Xl[s_kx][ii][s_bb] = xv[ii];
        }
        __syncthreads();

        #pragma unroll 4
        for (int ii = 0; ii < 16; ++ii) {
            float4 wr0 = *(const float4*)&Wr_l[ii][o8][kh << 3];
            float4 wr1 = *(const float4*)&Wr_l[ii][o8][(kh << 3) + 4];
            float4 wi0 = *(const float4*)&Wi_l[ii][o8][kh << 3];
            float4 wi1 = *(const float4*)&Wi_l[ii][o8][(kh << 3) + 4];
            const float wrv[8] = {wr0.x, wr0.y, wr0.z, wr0.w, wr1.x, wr1.y, wr1.z, wr1.w};
            const float wiv[8] = {wi0.x, wi0.y, wi0.z, wi0.w, wi1.x, wi1.y, wi1.z, wi1.w};
            #pragma unroll
            for (int j = 0; j < 8; ++j) {
                float2 xv = Xl[(kh << 3) + j][ii][b];
                acc[j].x = fmaf(xv.x, wrv[j], fmaf(-xv.y, wiv[j], acc[j].x));
                acc[j].y = fmaf(xv.x, wiv[j], fmaf( xv.y, wrv[j], acc[j].y));
            }
        }
    }

    const float sc = 1.52587890625e-05f;   // 1/65536
    const int o = (oc << 3) + o8;
    float2* sp = S + (((size_t)(b << 6) + o) << 9) + (kyIdx << 4) + (kh << 3);
    #pragma unroll
    for (int q = 0; q < 4; ++q) {
        float4 v = make_float4(acc[2 * q].x * sc, acc[2 * q].y * sc,
                               acc[2 * q + 1].x * sc, acc[2 * q + 1].y * sc);
        *(float4*)(sp + (q << 1)) = v;
    }
}

// ---------------- Pass 4: inverse DFT over h via MFMA (Z hi-only output) ----------------
static __device__ __forceinline__ void sb_put(ushort* Sbh, ushort* Sbl,
                                              int rr, int cc, float vv) {
    ushort hh, ll; split2(vv, hh, ll);
    int idx = (cc << 6) + ((((rr) >> 3) ^ (cc & 7)) << 3) + (rr & 7);
    Sbh[idx] = hh; Sbl[idx] = ll;
}

__global__ __launch_bounds__(256) void k_invh(const float2* __restrict__ S,
        const ushort* __restrict__ Th4h, const ushort* __restrict__ Th4l,
        ushort* __restrict__ Abh) {
    const int tid = threadIdx.x;
    const int lane = tid & 63;
    const int wv = tid >> 6;
    const int bid = blockIdx.x;
    const int bo = ((bid & 7) << 7) + (bid >> 3);     // XCD-chunked
    const int b = bo >> 6, o = bo & 63;
    const int l15 = lane & 15, l4 = lane >> 4;

    __shared__ ushort Sbh[2048];
    __shared__ ushort Sbl[2048];
    __shared__ float  Dl[256 * 33];

    {
        float4 sv = *(const float4*)(S + ((size_t)bo << 9) + (tid << 1));
        #pragma unroll
        for (int j = 0; j < 2; ++j) {
            int m = (tid << 1) + j;
            int ky = m >> 4, kx = m & 15;
            float sr = j ? sv.z : sv.x;
            float si = j ? sv.w : sv.y;
            float scl = kx ? 2.0f : 1.0f;
            sr *= scl; si *= scl;
            sb_put(Sbh, Sbl, ky,      kx,      sr);
            sb_put(Sbh, Sbl, 32 + ky, kx,     -si);
            sb_put(Sbh, Sbl, ky,      16 + kx, -si);
            sb_put(Sbh, Sbl, 32 + ky, 16 + kx, -sr);
        }
    }
    __syncthreads();

    f32x4 acc[4][2];
    #pragma unroll
    for (int i = 0; i < 4; ++i)
        #pragma unroll
        for (int nt = 0; nt < 2; ++nt)
            acc[i][nt] = (f32x4){0.f, 0.f, 0.f, 0.f};

    #pragma unroll
    for (int i = 0; i < 4; ++i) {
        const int hrow = (((wv << 2) + i) << 4) + l15;
        #pragma unroll
        for (int ks = 0; ks < 2; ++ks) {
            int aoff = (hrow << 6) + (ks << 5) + (l4 << 3);
            bf16x8 a_h = *(const bf16x8*)(Th4h + aoff);
            bf16x8 a_l = *(const bf16x8*)(Th4l + aoff);
            #pragma unroll
            for (int nt = 0; nt < 2; ++nt) {
                int col = (nt << 4) + l15;
                int oi = ((ks << 2) + l4) ^ (col & 7);
                bf16x8 b_h = *(const bf16x8*)(&Sbh[(col << 6) + (oi << 3)]);
                bf16x8 b_l = *(const bf16x8*)(&Sbl[(col << 6) + (oi << 3)]);
                acc[i][nt] = __builtin_amdgcn_mfma_f32_16x16x32_bf16(a_h, b_h, acc[i][nt], 0, 0, 0);
                acc[i][nt] = __builtin_amdgcn_mfma_f32_16x16x32_bf16(a_h, b_l, acc[i][nt], 0, 0, 0);
                acc[i][nt] = __builtin_amdgcn_mfma_f32_16x16x32_bf16(a_l, b_h, acc[i][nt], 0, 0, 0);
            }
        }
    }
    #pragma unroll
    for (int i = 0; i < 4; ++i)
        #pragma unroll
        for (int nt = 0; nt < 2; ++nt)
            #pragma unroll
            for (int r = 0; r < 4; ++r)
                Dl[((((wv << 2) + i) << 4) + (l4 << 2) + r) * 33 + (nt << 4) + l15]
                    = acc[i][nt][r];
    __syncthreads();

    {
        const int h = tid;
        ushort hi[32];
        #pragma unroll
        for (int j = 0; j < 32; ++j)
            hi[j] = bf16_rn(Dl[h * 33 + j]);
        size_t base = (((size_t)((b << 8) + h)) << 11) + (o << 5);
        *(uint4*)(Abh + base)      = *(uint4*)&hi[0];
        *(uint4*)(Abh + base + 8)  = *(uint4*)&hi[8];
        *(uint4*)(Abh + base + 16) = *(uint4*)&hi[16];
        *(uint4*)(Abh + base + 24) = *(uint4*)&hi[24];
    }
}

// ---------------- Pass 5: MFMA conv + inv-DFT-w + bias + GELU ----------------
// r7 schedule; B ([x | Tg]) hi-only, Z hi-only; A=Wc keeps hi/lo.
__global__ __launch_bounds__(256, 3) void k_final(const float* __restrict__ x,
        const ushort* __restrict__ Wch, const ushort* __restrict__ Wcl,
        const ushort* __restrict__ Tgh, const ushort* __restrict__ Tgl,
        const ushort* __restrict__ Abh,
        const float* __restrict__ bcv, float* __restrict__ out) {
    const int tid = threadIdx.x;
    const int lane = tid & 63;
    const int wv = tid >> 6;
    const int bid = blockIdx.x;
    const int gid = ((bid >> 5) << 3) | (bid & 7);
    const int wq  = (bid >> 3) & 3;
    const int b = gid >> 6, ht = gid & 63;
    const int w0 = wq << 6;

    __shared__ ushort Xh[64][128];

    const int l15 = lane & 15, l4 = lane >> 4;
    const int mt0 = (wv >> 1) << 1;
    const int nt0 = (wv & 1) << 1;
    const int wloc = tid & 63, cb0 = tid >> 6;

    const float* xb = x + ((size_t)b << 22) + ((size_t)(ht << 2) << 8) + w0 + wloc;

    float g[2][2][8];
    #pragma unroll
    for (int i = 0; i < 2; ++i) {
        const float* xpc = xb + ((size_t)(cb0 + (i << 2)) << 19);
        #pragma unroll
        for (int j = 0; j < 8; ++j) g[0][i][j] = xpc[(size_t)j << 16];
    }

    {
        size_t gg = ((size_t)(w0 + wloc) << 5) + (cb0 << 3);
        bf16x8 th = *(const bf16x8*)(Tgh + gg);
        int bidx = (8 + cb0) ^ (wloc & 7);
        *(bf16x8*)(&Xh[0][0] + (wloc << 7) + (bidx << 3)) = th;
    }

    bf16x8 aW[2][2][2];
    #pragma unroll
    for (int mi = 0; mi < 2; ++mi) {
        int o = ((mt0 + mi) << 4) + l15;
        #pragma unroll
        for (int ks = 0; ks < 2; ++ks) {
            size_t gg = ((size_t)o << 6) + (ks << 5) + (l4 << 3);
            aW[mi][ks][0] = *(const bf16x8*)(Wch + gg);
            aW[mi][ks][1] = *(const bf16x8*)(Wcl + gg);
        }
    }
    float bias[2][4];
    #pragma unroll
    for (int mi = 0; mi < 2; ++mi)
        #pragma unroll
        for (int r = 0; r < 4; ++r)
            bias[mi][r] = bcv[((mt0 + mi) << 4) + (l4 << 2) + r];

    #pragma unroll
    for (int hh = 0; hh < 4; ++hh) {
        const int h = (ht << 2) + hh;
        const int cur = hh & 1, nxt = cur ^ 1;

        bf16x8 zH[2];
        #pragma unroll
        for (int mi = 0; mi < 2; ++mi) {
            int o = ((mt0 + mi) << 4) + l15;
            size_t gg = ((((size_t)((b << 8) + h) << 6) + o) << 5) + (l4 << 3);
            zH[mi] = *(const bf16x8*)(Abh + gg);
        }

        bf16x8 hb[2];
        cvt8_hi(g[cur][0], hb[0]);
        cvt8_hi(g[cur][1], hb[1]);

        __syncthreads();
        #pragma unroll
        for (int i = 0; i < 2; ++i) {
            int bidx = (cb0 + (i << 2)) ^ (wloc & 7);
            *(bf16x8*)(&Xh[0][0] + (wloc << 7) + (bidx << 3)) = hb[i];
        }
        __syncthreads();

        // prefetch next h's x here: loads stay in flight through MFMA+epilogue
        // and the next iteration's Z-loads; drained at the NEXT barrier.
        if (hh < 3) {
            #pragma unroll
            for (int i = 0; i < 2; ++i) {
                const float* xpc = xb + ((size_t)(cb0 + (i << 2)) << 19) + ((hh + 1) << 8);
                #pragma unroll
                for (int j = 0; j < 8; ++j) g[nxt][i][j] = xpc[(size_t)j << 16];
            }
        }

        f32x4 acc[2][2];
        #pragma unroll
        for (int mi = 0; mi < 2; ++mi)
            #pragma unroll
            for (int ni = 0; ni < 2; ++ni)
                acc[mi][ni] = (f32x4){0.f, 0.f, 0.f, 0.f};

        #pragma unroll
        for (int ks = 0; ks < 3; ++ks) {
            bf16x8 bh[2];
            #pragma unroll
            for (int ni = 0; ni < 2; ++ni) {
                int w = ((nt0 + ni) << 4) + l15;
                int bidx = ((ks << 2) + l4) ^ (w & 7);
                bh[ni] = *(const bf16x8*)(&Xh[0][0] + (w << 7) + (bidx << 3));
            }
            #pragma unroll
            for (int mi = 0; mi < 2; ++mi) {
                if (ks < 2) {
                    #pragma unroll
                    for (int ni = 0; ni < 2; ++ni) {
                        acc[mi][ni] = __builtin_amdgcn_mfma_f32_16x16x32_bf16(aW[mi][ks][0], bh[ni], acc[mi][ni], 0, 0, 0);
                        acc[mi][ni] = __builtin_amdgcn_mfma_f32_16x16x32_bf16(aW[mi][ks][1], bh[ni], acc[mi][ni], 0, 0, 0);
                    }
                } else {
                    #pragma unroll
                    for (int ni = 0; ni < 2; ++ni) {
                        acc[mi][ni] = __builtin_amdgcn_mfma_f32_16x16x32_bf16(zH[mi], bh[ni], acc[mi][ni], 0, 0, 0);
                    }
                }
            }
        }

        #pragma unroll
        for (int mi = 0; mi < 2; ++mi) {
            #pragma unroll
            for (int ni = 0; ni < 2; ++ni) {
                int wg = w0 + ((nt0 + ni) << 4) + l15;
                #pragma unroll
                for (int r = 0; r < 4; ++r) {
                    int o = ((mt0 + mi) << 4) + (l4 << 2) + r;
                    float v = acc[mi][ni][r] + bias[mi][r];
                    out[((size_t)((b << 6) + o) << 16) + ((size_t)h << 8) + wg] = gelu_f(v);
                }
            }
        }
    }
}

extern "C" void kernel_launch(void* const* d_in, const int* in_sizes, int n_in,
                              void* d_out, int out_size, void* d_ws, size_t ws_size,
                              hipStream_t stream) {
    const float* x   = (const float*)d_in[0];
    const float* Wc  = (const float*)d_in[1];
    const float* bcv = (const float*)d_in[2];
    const float* w1r = (const float*)d_in[3];
    const float* w1i = (const float*)d_in[4];
    const float* w2r = (const float*)d_in[5];
    const float* w2i = (const float*)d_in[6];
    float* out = (float*)d_out;

    // Workspace (42.2 MB):
    //   [0, 16.8M):  Abh (pass4->5, hi-only)
    //   [33.5M):     XhT 4M    [37.7M): S 4M    [41.9M+): tables
    char* wsb = (char*)d_ws;
    ushort* Abh  = (ushort*)wsb;
    float2* XhT  = (float2*)(wsb + 33554432);
    float2* S    = (float2*)(wsb + 37748736);
    ushort* Wch  = (ushort*)(wsb + 41943040);
    ushort* Wcl  = (ushort*)(wsb + 41951232);
    ushort* Tgh  = (ushort*)(wsb + 41959424);
    ushort* Tgl  = (ushort*)(wsb + 41975808);
    ushort* Tkh  = (ushort*)(wsb + 41992192);
    ushort* Tkl  = (ushort*)(wsb + 42008576);
    ushort* Th2h = (ushort*)(wsb + 42024960);
    ushort* Th2l = (ushort*)(wsb + 42057728);
    ushort* Th4h = (ushort*)(wsb + 42090496);
    ushort* Th4l = (ushort*)(wsb + 42123264);

    k_prep <<< 208, 256, 0, stream>>>(Wc, Wch, Wcl, Tgh, Tgl, Tkh, Tkl,
                                      Th2h, Th2l, Th4h, Th4l);
    k_spec <<<1024, 256, 0, stream>>>(x, Tkh, Tkl, Th2h, Th2l, XhT);
    k_modes<<< 256, 256, 0, stream>>>(XhT, w1r, w1i, w2r, w2i, S);
    k_invh <<<1024, 256, 0, stream>>>(S, Th4h, Th4l, Abh);
    k_final<<<4096, 256, 0, stream>>>(x, Wch, Wcl, Tgh, Tgl, Abh, bcv, out);
}